// Round 3
// baseline (1922.572 us; speedup 1.0000x reference)
//
#include <hip/hip_runtime.h>

#define BB 8
#define NN 8192
#define SS 1024
#define KK 32
#define NPIX (BB*SS*KK)   // 262144
#define R2C 0.04f
#define EPS 1e-5f

#define FT 512            // fps threads
#define FW (FT/64)        // 8 waves
#define PPT (NN/FT)       // 16 points per thread
#define NCELL 4096        // 16^3 morton cells

// ---------- ws layout (bytes) ----------
#define OFF_IDX      0u
#define OFF_NEWXYZ   (OFF_IDX + BB*SS*4)
#define OFF_GIDX     (OFF_NEWXYZ + BB*SS*3*4)
#define OFF_XYZN     (OFF_GIDX + BB*SS*KK*4)
#define OFF_PTSN     (OFF_XYZN + BB*NN*3*4)
#define OFF_Y0       (OFF_PTSN + BB*NN*64*4)
#define OFF_Y1       (OFF_Y0 + NPIX*64*2)
#define OFF_MAXMIN   (OFF_Y1 + NPIX*64*2)
#define OFF_P0       (OFF_MAXMIN + BB*SS*128*2*4)
#define OFF_P1       (OFF_P0 + 1024*128*4)
#define OFF_P2       (OFF_P1 + 1024*128*4)
#define OFF_SC       (OFF_P2 + 1024*256*4)

__device__ __forceinline__ unsigned short f2bf(float x){
    unsigned u = __float_as_uint(x);
    unsigned r = (u + 0x7FFFu + ((u >> 16) & 1u)) >> 16;
    return (unsigned short)r;
}
__device__ __forceinline__ float bf2f(unsigned h){
    return __uint_as_float(h << 16);
}
__device__ __forceinline__ float sqdist3(float dx, float dy, float dz){
    // numpy order, no fma contraction: ((dx*dx)+(dy*dy))+(dz*dz)
    return __fadd_rn(__fadd_rn(__fmul_rn(dx,dx), __fmul_rn(dy,dy)), __fmul_rn(dz,dz));
}
__device__ __forceinline__ int spread4(int v){ // bits 0..3 -> 0,3,6,9
    return (v&1) | ((v&2)<<2) | ((v&4)<<4) | ((v&8)<<6);
}

// ---------- transpose: xyz (B,3,N)->(B,N,3), pts (B,64,N)->(B,N,64) ----------
__global__ __launch_bounds__(256) void t_kernel(const float* __restrict__ xyz,
                                                const float* __restrict__ pts,
                                                float* __restrict__ xyz_n,
                                                float* __restrict__ pts_n){
    int gid = blockIdx.x * 256 + threadIdx.x;   // 65536 = B*N
    int b = gid >> 13, i = gid & (NN - 1);
    const float* xb = xyz + (size_t)b * 3 * NN;
    float x = xb[i], y = xb[NN + i], z = xb[2 * NN + i];
    float* xd = xyz_n + ((size_t)b * NN + i) * 3;
    xd[0] = x; xd[1] = y; xd[2] = z;
    const float* pb = pts + (size_t)b * 64 * NN + i;
    float4* pd = (float4*)(pts_n + ((size_t)b * NN + i) * 64);
#pragma unroll
    for (int q = 0; q < 16; ++q){
        float4 v;
        v.x = pb[(q*4+0)*NN]; v.y = pb[(q*4+1)*NN];
        v.z = pb[(q*4+2)*NN]; v.w = pb[(q*4+3)*NN];
        pd[q] = v;
    }
}

// ---------- FPS: morton-sorted chunks + exact bbox pruning ----------
__global__ __launch_bounds__(FT) void fps_kernel(const float* __restrict__ xyz,
                                                 float* __restrict__ newxyz,
                                                 float* __restrict__ out){
    __shared__ float sx[NN], sy[NN], sz[NN];     // original-index order
    __shared__ int   si[NN];                     // sorted -> original idx
    __shared__ int   hist[NCELL];
    __shared__ int   waveTot[FW];
    __shared__ unsigned long long slots[2][FW];
    int b = blockIdx.x, tid = threadIdx.x;
    int wave = tid >> 6, lane = tid & 63;
    const float* xb = xyz + (size_t)b * 3 * NN;

    // ---- load coords to LDS (original order) + compute morton cells ----
    float xx[PPT], yy[PPT], zz[PPT];
    int cell[PPT];
#pragma unroll
    for (int j = 0; j < PPT; ++j){
        int i = tid + j * FT;
        float x = xb[i], y = xb[NN + i], z = xb[2*NN + i];
        sx[i] = x; sy[i] = y; sz[i] = z;
        xx[j] = x; yy[j] = y; zz[j] = z;
        int cx = min(15, max(0, (int)(x * 16.f)));
        int cy = min(15, max(0, (int)(y * 16.f)));
        int cz = min(15, max(0, (int)(z * 16.f)));
        cell[j] = spread4(cx) | (spread4(cy) << 1) | (spread4(cz) << 2);
    }
    // ---- histogram ----
#pragma unroll
    for (int k = 0; k < NCELL/FT; ++k) hist[tid * (NCELL/FT) + k] = 0;
    __syncthreads();
#pragma unroll
    for (int j = 0; j < PPT; ++j) atomicAdd(&hist[cell[j]], 1);
    __syncthreads();
    // ---- exclusive scan over 4096 cells ----
    {
        int base0 = tid * (NCELL/FT);
        int sum8 = 0;
#pragma unroll
        for (int k = 0; k < NCELL/FT; ++k) sum8 += hist[base0 + k];
        int s = sum8;
#pragma unroll
        for (int m = 1; m < 64; m <<= 1){
            int v = __shfl_up(s, m);
            if (lane >= m) s += v;
        }
        if (lane == 63) waveTot[wave] = s;
        __syncthreads();
        int wbase = 0;
        for (int w2 = 0; w2 < FW; ++w2) if (w2 < wave) wbase += waveTot[w2];
        int run = wbase + s - sum8;
#pragma unroll
        for (int k = 0; k < NCELL/FT; ++k){
            int h = hist[base0 + k];
            hist[base0 + k] = run;
            run += h;
        }
    }
    __syncthreads();
    // ---- scatter permutation ----
#pragma unroll
    for (int j = 0; j < PPT; ++j){
        int pos = atomicAdd(&hist[cell[j]], 1);
        si[pos] = tid + j * FT;
    }
    __syncthreads();
    // ---- gather thread's contiguous sorted chunk + bbox ----
    float px[PPT], py[PPT], pz[PPT], dist[PPT];
    int oi[PPT];
    float bxmin =  1e30f, bxmax = -1e30f;
    float bymin =  1e30f, bymax = -1e30f;
    float bzmin =  1e30f, bzmax = -1e30f;
#pragma unroll
    for (int j = 0; j < PPT; ++j){
        int g = si[tid * PPT + j];
        oi[j] = g;
        float x = sx[g], y = sy[g], z = sz[g];
        px[j] = x; py[j] = y; pz[j] = z;
        bxmin = fminf(bxmin, x); bxmax = fmaxf(bxmax, x);
        bymin = fminf(bymin, y); bymax = fmaxf(bymax, y);
        bzmin = fminf(bzmin, z); bzmax = fmaxf(bzmax, z);
        dist[j] = __int_as_float(0x7f800000); // +inf
    }
    __syncthreads();

    unsigned long long mykey = 0ull, myWaveKey = 0ull;
    float tmax = __int_as_float(0x7f800000);
    int w = 0;
    for (int t = 0; t < SS; ++t){
        float lx = sx[w], ly = sy[w], lz = sz[w];
        if (tid == 0){
            out[(size_t)b * 3 * SS + t]          = lx;
            out[(size_t)b * 3 * SS + SS + t]     = ly;
            out[(size_t)b * 3 * SS + 2*SS + t]   = lz;
            float* nw = newxyz + ((size_t)b * SS + t) * 3;
            nw[0] = lx; nw[1] = ly; nw[2] = lz;
        }
        // exact-safe bbox prune: d_bb <= d_p (f32, same rounding order) for all p in chunk
        float cdx = __fsub_rn(lx, fminf(fmaxf(lx, bxmin), bxmax));
        float cdy = __fsub_rn(ly, fminf(fmaxf(ly, bymin), bymax));
        float cdz = __fsub_rn(lz, fminf(fmaxf(lz, bzmin), bzmax));
        float d_bb = sqdist3(cdx, cdy, cdz);
        bool active = d_bb < tmax;
        unsigned long long bal = __ballot(active);
        if (active){
            float maxd = -1.f;
            {
#pragma clang fp contract(off)
#pragma unroll
                for (int j = 0; j < PPT; ++j){
                    float dx = px[j] - lx;
                    float dy = py[j] - ly;
                    float dz = pz[j] - lz;
                    float d = ((dx*dx) + (dy*dy)) + (dz*dz);
                    float nd = fminf(dist[j], d);
                    dist[j] = nd;
                    maxd = fmaxf(maxd, nd);
                }
            }
            int bo = 0x7fffffff;
#pragma unroll
            for (int j = 0; j < PPT; ++j)
                if (dist[j] == maxd) bo = min(bo, oi[j]);
            mykey = ((unsigned long long)__float_as_uint(maxd) << 32)
                  | (unsigned)(~bo);
            tmax = maxd;
        }
        int cur = t & 1;
        if (bal){
            unsigned long long k = mykey;
#pragma unroll
            for (int m = 1; m <= 32; m <<= 1){
                unsigned long long ok = __shfl_xor(k, m);
                k = (ok > k) ? ok : k;
            }
            if (lane == 0) slots[cur][wave] = k;
        } else {
            if (lane == 0) slots[cur][wave] = myWaveKey;
        }
        __syncthreads();
        unsigned long long km = slots[cur][0];
#pragma unroll
        for (int q = 1; q < FW; ++q){
            unsigned long long ok = slots[cur][q];
            km = (ok > km) ? ok : km;
        }
        myWaveKey = slots[cur][wave];
        w = (int)(~(unsigned)km);
    }
}

// ---------- query ball: one wave per sample, planar coalesced reads ----------
__global__ __launch_bounds__(256) void qb_kernel(const float* __restrict__ xyz,
                                                 const float* __restrict__ newxyz,
                                                 int* __restrict__ gidx){
    int wid = (blockIdx.x * 256 + threadIdx.x) >> 6;  // sample id 0..8191
    int lane = threadIdx.x & 63;
    int b = wid >> 10;
    const float* nw = newxyz + (size_t)wid * 3;
    float cx = nw[0], cy = nw[1], cz = nw[2];
    const float* xb = xyz + (size_t)b * 3 * NN;
    int total = 0, firstIdx = -1;
    int* gout = gidx + (size_t)wid * KK;
    for (int base = 0; base < NN; base += 64){
        int i = base + lane;
        float dx = __fsub_rn(cx, xb[i]);
        float dy = __fsub_rn(cy, xb[NN + i]);
        float dz = __fsub_rn(cz, xb[2*NN + i]);
        float d2 = sqdist3(dx, dy, dz);
        bool in = (d2 <= R2C);
        unsigned long long m = __ballot(in);
        int pos = total + __popcll(m & ((1ull << lane) - 1ull));
        if (in && pos < KK) gout[pos] = i;
        if (firstIdx < 0 && m) firstIdx = base + (__ffsll((unsigned long long)m) - 1);
        total += __popcll(m);
        if (total >= KK) break;
    }
    if (total < KK){
        int f = (total > 0) ? firstIdx : (NN - 1);
        for (int p = total + lane; p < KK; p += 64) gout[p] = f;
    }
}

// ---------- layer0: gather + 67->64 matmul + stats ----------
__global__ __launch_bounds__(256) void l0_kernel(const float* __restrict__ pts_n,
                                                 const float* __restrict__ xyz_n,
                                                 const float* __restrict__ newxyz,
                                                 const int* __restrict__ gidx,
                                                 const float* __restrict__ W0,
                                                 const float* __restrict__ b0,
                                                 uint4* __restrict__ y0,
                                                 float* __restrict__ part0){
    __shared__ float lsum[4][64][2];
    int tid = threadIdx.x;
    int pixel = blockIdx.x * 256 + tid;
    int sample = pixel >> 5;
    int b = sample >> 10;
    int gi = gidx[pixel];
    int wave = tid >> 6, lane = tid & 63;

    float ff[67];
    const float4* prow = (const float4*)(pts_n + ((size_t)b * NN + gi) * 64);
#pragma unroll
    for (int q = 0; q < 16; ++q){
        float4 v = prow[q];
        ff[q*4] = v.x; ff[q*4+1] = v.y; ff[q*4+2] = v.z; ff[q*4+3] = v.w;
    }
    const float* pr = xyz_n + ((size_t)b * NN + gi) * 3;
    const float* nw = newxyz + (size_t)sample * 3;
    ff[64] = __fsub_rn(pr[0], nw[0]) / 0.2f;
    ff[65] = __fsub_rn(pr[1], nw[1]) / 0.2f;
    ff[66] = __fsub_rn(pr[2], nw[2]) / 0.2f;

    for (int oc = 0; oc < 8; ++oc){
        float acc[8];
#pragma unroll
        for (int j = 0; j < 8; ++j) acc[j] = b0[oc*8+j];
#pragma unroll
        for (int c = 0; c < 67; ++c){
            float fe = ff[c];
#pragma unroll
            for (int j = 0; j < 8; ++j) acc[j] += fe * W0[(oc*8+j)*67 + c];
        }
        uint4 pk;
        unsigned us[8];
#pragma unroll
        for (int j = 0; j < 8; ++j){
            float v = acc[j];
            float s1 = v, s2 = v * v;
#pragma unroll
            for (int m = 1; m <= 32; m <<= 1){
                s1 += __shfl_xor(s1, m);
                s2 += __shfl_xor(s2, m);
            }
            if (lane == 0){ lsum[wave][oc*8+j][0] = s1; lsum[wave][oc*8+j][1] = s2; }
            us[j] = f2bf(v);
        }
        pk.x = us[0] | (us[1] << 16);
        pk.y = us[2] | (us[3] << 16);
        pk.z = us[4] | (us[5] << 16);
        pk.w = us[6] | (us[7] << 16);
        y0[(size_t)pixel * 8 + oc] = pk;
    }
    __syncthreads();
    if (tid < 128){
        float s = lsum[0][tid>>1][tid&1] + lsum[1][tid>>1][tid&1]
                + lsum[2][tid>>1][tid&1] + lsum[3][tid>>1][tid&1];
        part0[(size_t)blockIdx.x * 128 + tid] = s;
    }
}

// ---------- layer1: bn+relu + 64->64 matmul + stats ----------
__global__ __launch_bounds__(256) void l1_kernel(const uint4* __restrict__ y0,
                                                 const float* __restrict__ scale0,
                                                 const float* __restrict__ shift0,
                                                 const float* __restrict__ W1,
                                                 const float* __restrict__ b1,
                                                 uint4* __restrict__ y1,
                                                 float* __restrict__ part1){
    __shared__ float lsum[4][64][2];
    int tid = threadIdx.x;
    int pixel = blockIdx.x * 256 + tid;
    int wave = tid >> 6, lane = tid & 63;

    float x[64];
#pragma unroll
    for (int q = 0; q < 8; ++q){
        uint4 v = y0[(size_t)pixel * 8 + q];
        unsigned w[4] = {v.x, v.y, v.z, v.w};
#pragma unroll
        for (int r = 0; r < 4; ++r){
            int c = q*8 + r*2;
            x[c]   = fmaxf(bf2f(w[r] & 0xFFFFu) * scale0[c]   + shift0[c],   0.f);
            x[c+1] = fmaxf(bf2f(w[r] >> 16)     * scale0[c+1] + shift0[c+1], 0.f);
        }
    }
    for (int oc = 0; oc < 8; ++oc){
        float acc[8];
#pragma unroll
        for (int j = 0; j < 8; ++j) acc[j] = b1[oc*8+j];
#pragma unroll
        for (int c = 0; c < 64; ++c){
            float fe = x[c];
#pragma unroll
            for (int j = 0; j < 8; ++j) acc[j] += fe * W1[(oc*8+j)*64 + c];
        }
        uint4 pk;
        unsigned us[8];
#pragma unroll
        for (int j = 0; j < 8; ++j){
            float v = acc[j];
            float s1 = v, s2 = v * v;
#pragma unroll
            for (int m = 1; m <= 32; m <<= 1){
                s1 += __shfl_xor(s1, m);
                s2 += __shfl_xor(s2, m);
            }
            if (lane == 0){ lsum[wave][oc*8+j][0] = s1; lsum[wave][oc*8+j][1] = s2; }
            us[j] = f2bf(v);
        }
        pk.x = us[0] | (us[1] << 16);
        pk.y = us[2] | (us[3] << 16);
        pk.z = us[4] | (us[5] << 16);
        pk.w = us[6] | (us[7] << 16);
        y1[(size_t)pixel * 8 + oc] = pk;
    }
    __syncthreads();
    if (tid < 128){
        float s = lsum[0][tid>>1][tid&1] + lsum[1][tid>>1][tid&1]
                + lsum[2][tid>>1][tid&1] + lsum[3][tid>>1][tid&1];
        part1[(size_t)blockIdx.x * 128 + tid] = s;
    }
}

// ---------- layer2: bn+relu + 64->128 matmul + k-max/min + stats ----------
__global__ __launch_bounds__(256) void l2_kernel(const uint4* __restrict__ y1,
                                                 const float* __restrict__ scale1,
                                                 const float* __restrict__ shift1,
                                                 const float* __restrict__ W2,
                                                 const float* __restrict__ b2,
                                                 float* __restrict__ maxmin,
                                                 float* __restrict__ part2){
    __shared__ float lsum[4][128][2];
    int tid = threadIdx.x;
    int pixel = blockIdx.x * 256 + tid;
    int sample = pixel >> 5;
    int wave = tid >> 6, lane = tid & 63;

    float x[64];
#pragma unroll
    for (int q = 0; q < 8; ++q){
        uint4 v = y1[(size_t)pixel * 8 + q];
        unsigned w[4] = {v.x, v.y, v.z, v.w};
#pragma unroll
        for (int r = 0; r < 4; ++r){
            int c = q*8 + r*2;
            x[c]   = fmaxf(bf2f(w[r] & 0xFFFFu) * scale1[c]   + shift1[c],   0.f);
            x[c+1] = fmaxf(bf2f(w[r] >> 16)     * scale1[c+1] + shift1[c+1], 0.f);
        }
    }
    for (int oc = 0; oc < 16; ++oc){
        float acc[8];
#pragma unroll
        for (int j = 0; j < 8; ++j) acc[j] = b2[oc*8+j];
#pragma unroll
        for (int c = 0; c < 64; ++c){
            float fe = x[c];
#pragma unroll
            for (int j = 0; j < 8; ++j) acc[j] += fe * W2[(oc*8+j)*64 + c];
        }
#pragma unroll
        for (int j = 0; j < 8; ++j){
            float v = acc[j];
            int ch = oc*8 + j;
            float mx = v, mn = v;
#pragma unroll
            for (int m = 1; m <= 16; m <<= 1){
                mx = fmaxf(mx, __shfl_xor(mx, m));
                mn = fminf(mn, __shfl_xor(mn, m));
            }
            float s1 = v, s2 = v * v;
#pragma unroll
            for (int m = 1; m <= 32; m <<= 1){
                s1 += __shfl_xor(s1, m);
                s2 += __shfl_xor(s2, m);
            }
            if (lane == 0){ lsum[wave][ch][0] = s1; lsum[wave][ch][1] = s2; }
            if ((tid & 31) == 0){
                float* mm = maxmin + ((size_t)sample * 128 + ch) * 2;
                mm[0] = mx; mm[1] = mn;
            }
        }
    }
    __syncthreads();
    {
        float s = lsum[0][tid>>1][tid&1] + lsum[1][tid>>1][tid&1]
                + lsum[2][tid>>1][tid&1] + lsum[3][tid>>1][tid&1];
        part2[(size_t)blockIdx.x * 256 + tid] = s;
    }
}

// ---------- finalize BN params (parallel: 1024 threads) ----------
__global__ __launch_bounds__(1024) void fin_kernel(const float* __restrict__ part, int O,
                           const float* __restrict__ g, const float* __restrict__ be,
                           float* __restrict__ scale, float* __restrict__ shift){
    __shared__ float ls[1024];
    __shared__ float tot[256];
    int tid = threadIdx.x;
    int M = 2 * O;               // 128 or 256
    int C = 1024 / M;            // 8 or 4 chunks
    int m = tid & (M - 1);
    int chunk = tid / M;
    int per = 1024 / C;          // blocks per chunk
    float s = 0.f;
    for (int r = 0; r < per; ++r){
        int blk = chunk * per + r;
        s += part[(size_t)blk * M + m];
    }
    ls[tid] = s;
    __syncthreads();
    if (tid < M){
        float tt = 0.f;
        for (int c2 = 0; c2 < C; ++c2) tt += ls[c2 * M + tid];
        tot[tid] = tt;
    }
    __syncthreads();
    if (tid < O){
        float s1 = tot[2*tid], s2 = tot[2*tid+1];
        float inv = 1.0f / (float)NPIX;
        float mu = s1 * inv;
        float var = s2 * inv - mu * mu;
        float rs = 1.0f / sqrtf(var + EPS);
        float sc = rs * g[tid];
        scale[tid] = sc;
        shift[tid] = be[tid] - mu * sc;
    }
}

// ---------- output: apply BN to max/min, relu, transpose write ----------
__global__ __launch_bounds__(256) void out_kernel(const float* __restrict__ maxmin,
                                                  const float* __restrict__ scale2,
                                                  const float* __restrict__ shift2,
                                                  float* __restrict__ out){
    int gid = blockIdx.x * 256 + threadIdx.x;  // 1048576, layout (b,o,s)
    int s = gid & 1023;
    int o = (gid >> 10) & 127;
    int b = gid >> 17;
    int sample = b * 1024 + s;
    float2 mm = ((const float2*)maxmin)[(size_t)sample * 128 + o];
    float sc = scale2[o], sh = shift2[o];
    float v = (sc >= 0.f) ? mm.x : mm.y;
    out[gid] = fmaxf(v * sc + sh, 0.f);
}

extern "C" void kernel_launch(void* const* d_in, const int* in_sizes, int n_in,
                              void* d_out, int out_size, void* d_ws, size_t ws_size,
                              hipStream_t stream) {
    const float* xyz = (const float*)d_in[0];
    const float* pts = (const float*)d_in[1];
    const float* W0 = (const float*)d_in[2];
    const float* b0 = (const float*)d_in[3];
    const float* g0 = (const float*)d_in[4];
    const float* be0 = (const float*)d_in[5];
    const float* W1 = (const float*)d_in[6];
    const float* b1 = (const float*)d_in[7];
    const float* g1 = (const float*)d_in[8];
    const float* be1 = (const float*)d_in[9];
    const float* W2 = (const float*)d_in[10];
    const float* b2 = (const float*)d_in[11];
    const float* g2 = (const float*)d_in[12];
    const float* be2 = (const float*)d_in[13];

    char* ws = (char*)d_ws;
    float* newxyz = (float*)(ws + OFF_NEWXYZ);
    int*   gidx   = (int*)(ws + OFF_GIDX);
    float* xyz_n  = (float*)(ws + OFF_XYZN);
    float* pts_n  = (float*)(ws + OFF_PTSN);
    uint4* y0     = (uint4*)(ws + OFF_Y0);
    uint4* y1     = (uint4*)(ws + OFF_Y1);
    float* maxmin = (float*)(ws + OFF_MAXMIN);
    float* part0  = (float*)(ws + OFF_P0);
    float* part1  = (float*)(ws + OFF_P1);
    float* part2  = (float*)(ws + OFF_P2);
    float* sc     = (float*)(ws + OFF_SC);
    float* scale0 = sc,        *shift0 = sc + 64;
    float* scale1 = sc + 128,  *shift1 = sc + 192;
    float* scale2 = sc + 256,  *shift2 = sc + 384;

    float* out = (float*)d_out;
    float* out_np = out + BB * 3 * SS;

    hipLaunchKernelGGL(t_kernel, dim3(256), dim3(256), 0, stream, xyz, pts, xyz_n, pts_n);
    hipLaunchKernelGGL(fps_kernel, dim3(BB), dim3(FT), 0, stream, xyz, newxyz, out);
    hipLaunchKernelGGL(qb_kernel, dim3(2048), dim3(256), 0, stream, xyz, newxyz, gidx);
    hipLaunchKernelGGL(l0_kernel, dim3(1024), dim3(256), 0, stream,
                       pts_n, xyz_n, newxyz, gidx, W0, b0, y0, part0);
    hipLaunchKernelGGL(fin_kernel, dim3(1), dim3(1024), 0, stream, part0, 64, g0, be0, scale0, shift0);
    hipLaunchKernelGGL(l1_kernel, dim3(1024), dim3(256), 0, stream,
                       y0, scale0, shift0, W1, b1, y1, part1);
    hipLaunchKernelGGL(fin_kernel, dim3(1), dim3(1024), 0, stream, part1, 64, g1, be1, scale1, shift1);
    hipLaunchKernelGGL(l2_kernel, dim3(1024), dim3(256), 0, stream,
                       y1, scale1, shift1, W2, b2, maxmin, part2);
    hipLaunchKernelGGL(fin_kernel, dim3(1), dim3(1024), 0, stream, part2, 128, g2, be2, scale2, shift2);
    hipLaunchKernelGGL(out_kernel, dim3(4096), dim3(256), 0, stream, maxmin, scale2, shift2, out_np);
}

// Round 4
// 1735.184 us; speedup vs baseline: 1.1080x; 1.1080x over previous
//
#include <hip/hip_runtime.h>

#define BB 8
#define NN 8192
#define SS 1024
#define KK 32
#define NPIX (BB*SS*KK)   // 262144
#define R2C 0.04f
#define EPS 1e-5f

#define FT 512            // fps threads
#define FW (FT/64)        // 8 waves
#define PPT (NN/FT)       // 16 points per thread
#define NCELL 4096        // 16^3 morton cells

// ---------- ws layout (bytes) ----------
#define OFF_IDX      0u
#define OFF_NEWXYZ   (OFF_IDX + BB*SS*4)
#define OFF_GIDX     (OFF_NEWXYZ + BB*SS*3*4)
#define OFF_XYZN     (OFF_GIDX + BB*SS*KK*4)
#define OFF_PTSN     (OFF_XYZN + BB*NN*3*4)
#define OFF_Y0       (OFF_PTSN + BB*NN*64*4)
#define OFF_Y1       (OFF_Y0 + NPIX*64*2)
#define OFF_MAXMIN   (OFF_Y1 + NPIX*64*2)
#define OFF_P0       (OFF_MAXMIN + BB*SS*128*2*4)
#define OFF_P1       (OFF_P0 + 1024*128*4)
#define OFF_P2       (OFF_P1 + 1024*128*4)
#define OFF_SC       (OFF_P2 + 1024*256*4)

__device__ __forceinline__ unsigned short f2bf(float x){
    unsigned u = __float_as_uint(x);
    unsigned r = (u + 0x7FFFu + ((u >> 16) & 1u)) >> 16;
    return (unsigned short)r;
}
__device__ __forceinline__ float bf2f(unsigned h){
    return __uint_as_float(h << 16);
}
__device__ __forceinline__ float sqdist3(float dx, float dy, float dz){
    // numpy order, no fma contraction: ((dx*dx)+(dy*dy))+(dz*dz)
    return __fadd_rn(__fadd_rn(__fmul_rn(dx,dx), __fmul_rn(dy,dy)), __fmul_rn(dz,dz));
}
__device__ __forceinline__ int spread4(int v){ // bits 0..3 -> 0,3,6,9
    return (v&1) | ((v&2)<<2) | ((v&4)<<4) | ((v&8)<<6);
}

// DPP u64 max step: VALU-speed cross-lane (no LDS pipe round-trip)
template<int CTRL>
__device__ __forceinline__ unsigned long long dpp_max_step(unsigned long long k){
    int lo = (int)(unsigned)k;
    int hi = (int)(unsigned)(k >> 32);
    int olo = __builtin_amdgcn_update_dpp(0, lo, CTRL, 0xf, 0xf, true);
    int ohi = __builtin_amdgcn_update_dpp(0, hi, CTRL, 0xf, 0xf, true);
    unsigned long long o = ((unsigned long long)(unsigned)ohi << 32) | (unsigned)olo;
    return (o > k) ? o : k;
}
// after this, lane 63 holds the wave-wide max (keys are nonneg, 0 is identity)
__device__ __forceinline__ unsigned long long wave_max_u64(unsigned long long k){
    k = dpp_max_step<0x111>(k); // row_shr:1
    k = dpp_max_step<0x112>(k); // row_shr:2
    k = dpp_max_step<0x114>(k); // row_shr:4
    k = dpp_max_step<0x118>(k); // row_shr:8  -> lane15 of each row = row max
    k = dpp_max_step<0x142>(k); // row_bcast15
    k = dpp_max_step<0x143>(k); // row_bcast31 -> lane63 = full wave max
    return k;
}

// ---------- transpose: xyz (B,3,N)->(B,N,3), pts (B,64,N)->(B,N,64) ----------
__global__ __launch_bounds__(256) void t_kernel(const float* __restrict__ xyz,
                                                const float* __restrict__ pts,
                                                float* __restrict__ xyz_n,
                                                float* __restrict__ pts_n){
    int gid = blockIdx.x * 256 + threadIdx.x;   // 65536 = B*N
    int b = gid >> 13, i = gid & (NN - 1);
    const float* xb = xyz + (size_t)b * 3 * NN;
    float x = xb[i], y = xb[NN + i], z = xb[2 * NN + i];
    float* xd = xyz_n + ((size_t)b * NN + i) * 3;
    xd[0] = x; xd[1] = y; xd[2] = z;
    const float* pb = pts + (size_t)b * 64 * NN + i;
    float4* pd = (float4*)(pts_n + ((size_t)b * NN + i) * 64);
#pragma unroll
    for (int q = 0; q < 16; ++q){
        float4 v;
        v.x = pb[(q*4+0)*NN]; v.y = pb[(q*4+1)*NN];
        v.z = pb[(q*4+2)*NN]; v.w = pb[(q*4+3)*NN];
        pd[q] = v;
    }
}

// ---------- FPS: morton-sorted chunks + exact bbox pruning + DPP reduce ----------
__global__ __launch_bounds__(FT) void fps_kernel(const float* __restrict__ xyz,
                                                 float* __restrict__ newxyz,
                                                 float* __restrict__ out){
    __shared__ float sx[NN], sy[NN], sz[NN];     // original-index order
    __shared__ int   si[NN];                     // sorted -> original idx
    __shared__ int   hist[NCELL];
    __shared__ int   waveTot[FW];
    __shared__ unsigned long long slots[2][FW];
    int b = blockIdx.x, tid = threadIdx.x;
    int wave = tid >> 6, lane = tid & 63;
    const float* xb = xyz + (size_t)b * 3 * NN;

    // ---- load coords to LDS (original order) + compute morton cells ----
    int cell[PPT];
#pragma unroll
    for (int j = 0; j < PPT; ++j){
        int i = tid + j * FT;
        float x = xb[i], y = xb[NN + i], z = xb[2*NN + i];
        sx[i] = x; sy[i] = y; sz[i] = z;
        int cx = min(15, max(0, (int)(x * 16.f)));
        int cy = min(15, max(0, (int)(y * 16.f)));
        int cz = min(15, max(0, (int)(z * 16.f)));
        cell[j] = spread4(cx) | (spread4(cy) << 1) | (spread4(cz) << 2);
    }
    // ---- histogram ----
#pragma unroll
    for (int k = 0; k < NCELL/FT; ++k) hist[tid * (NCELL/FT) + k] = 0;
    __syncthreads();
#pragma unroll
    for (int j = 0; j < PPT; ++j) atomicAdd(&hist[cell[j]], 1);
    __syncthreads();
    // ---- exclusive scan over 4096 cells ----
    {
        int base0 = tid * (NCELL/FT);
        int sum8 = 0;
#pragma unroll
        for (int k = 0; k < NCELL/FT; ++k) sum8 += hist[base0 + k];
        int s = sum8;
#pragma unroll
        for (int m = 1; m < 64; m <<= 1){
            int v = __shfl_up(s, m);
            if (lane >= m) s += v;
        }
        if (lane == 63) waveTot[wave] = s;
        __syncthreads();
        int wbase = 0;
        for (int w2 = 0; w2 < FW; ++w2) if (w2 < wave) wbase += waveTot[w2];
        int run = wbase + s - sum8;
#pragma unroll
        for (int k = 0; k < NCELL/FT; ++k){
            int h = hist[base0 + k];
            hist[base0 + k] = run;
            run += h;
        }
    }
    __syncthreads();
    // ---- scatter permutation ----
#pragma unroll
    for (int j = 0; j < PPT; ++j){
        int pos = atomicAdd(&hist[cell[j]], 1);
        si[pos] = tid + j * FT;
    }
    __syncthreads();
    // ---- gather thread's contiguous sorted chunk + bbox ----
    float px[PPT], py[PPT], pz[PPT], dist[PPT];
    int oi[PPT];
    float bxmin =  1e30f, bxmax = -1e30f;
    float bymin =  1e30f, bymax = -1e30f;
    float bzmin =  1e30f, bzmax = -1e30f;
#pragma unroll
    for (int j = 0; j < PPT; ++j){
        int g = si[tid * PPT + j];
        oi[j] = g;
        float x = sx[g], y = sy[g], z = sz[g];
        px[j] = x; py[j] = y; pz[j] = z;
        bxmin = fminf(bxmin, x); bxmax = fmaxf(bxmax, x);
        bymin = fminf(bymin, y); bymax = fmaxf(bymax, y);
        bzmin = fminf(bzmin, z); bzmax = fmaxf(bzmax, z);
        dist[j] = __int_as_float(0x7f800000); // +inf
    }
    __syncthreads();

    unsigned long long mykey = 0ull, myWaveKey = 0ull;
    float tmax = __int_as_float(0x7f800000);
    int w = 0;
    for (int t = 0; t < SS; ++t){
        float lx = sx[w], ly = sy[w], lz = sz[w];
        if (tid == 0){
            out[(size_t)b * 3 * SS + t]          = lx;
            out[(size_t)b * 3 * SS + SS + t]     = ly;
            out[(size_t)b * 3 * SS + 2*SS + t]   = lz;
            float* nw = newxyz + ((size_t)b * SS + t) * 3;
            nw[0] = lx; nw[1] = ly; nw[2] = lz;
        }
        // exact-safe bbox prune: d_bb <= d_p (f32, same rounding order) for all p in chunk
        float cdx = __fsub_rn(lx, fminf(fmaxf(lx, bxmin), bxmax));
        float cdy = __fsub_rn(ly, fminf(fmaxf(ly, bymin), bymax));
        float cdz = __fsub_rn(lz, fminf(fmaxf(lz, bzmin), bzmax));
        float d_bb = sqdist3(cdx, cdy, cdz);
        bool active = d_bb < tmax;
        unsigned long long bal = __ballot(active);
        if (active){
            float maxd = -1.f;
            {
#pragma clang fp contract(off)
#pragma unroll
                for (int j = 0; j < PPT; ++j){
                    float dx = px[j] - lx;
                    float dy = py[j] - ly;
                    float dz = pz[j] - lz;
                    float d = ((dx*dx) + (dy*dy)) + (dz*dz);
                    float nd = fminf(dist[j], d);
                    dist[j] = nd;
                    maxd = fmaxf(maxd, nd);
                }
            }
            int bo = 0x7fffffff;
#pragma unroll
            for (int j = 0; j < PPT; ++j)
                if (dist[j] == maxd) bo = min(bo, oi[j]);
            mykey = ((unsigned long long)__float_as_uint(maxd) << 32)
                  | (unsigned)(~bo);
            tmax = maxd;
        }
        int cur = t & 1;
        if (bal){
            unsigned long long k = wave_max_u64(mykey);
            if (lane == 63) slots[cur][wave] = k;
        } else {
            if (lane == 63) slots[cur][wave] = myWaveKey;
        }
        __syncthreads();
        unsigned long long s0 = slots[cur][0], s1 = slots[cur][1];
        unsigned long long s2 = slots[cur][2], s3 = slots[cur][3];
        unsigned long long s4 = slots[cur][4], s5 = slots[cur][5];
        unsigned long long s6 = slots[cur][6], s7 = slots[cur][7];
        unsigned long long a0 = (s1 > s0) ? s1 : s0;
        unsigned long long a1 = (s3 > s2) ? s3 : s2;
        unsigned long long a2 = (s5 > s4) ? s5 : s4;
        unsigned long long a3 = (s7 > s6) ? s7 : s6;
        a0 = (a1 > a0) ? a1 : a0;
        a2 = (a3 > a2) ? a3 : a2;
        unsigned long long km = (a2 > a0) ? a2 : a0;
        myWaveKey = slots[cur][wave];
        w = (int)(~(unsigned)km);
    }
}

// ---------- query ball: one wave per sample, planar coalesced reads ----------
__global__ __launch_bounds__(256) void qb_kernel(const float* __restrict__ xyz,
                                                 const float* __restrict__ newxyz,
                                                 int* __restrict__ gidx){
    int wid = (blockIdx.x * 256 + threadIdx.x) >> 6;  // sample id 0..8191
    int lane = threadIdx.x & 63;
    int b = wid >> 10;
    const float* nw = newxyz + (size_t)wid * 3;
    float cx = nw[0], cy = nw[1], cz = nw[2];
    const float* xb = xyz + (size_t)b * 3 * NN;
    int total = 0, firstIdx = -1;
    int* gout = gidx + (size_t)wid * KK;
    for (int base = 0; base < NN; base += 64){
        int i = base + lane;
        float dx = __fsub_rn(cx, xb[i]);
        float dy = __fsub_rn(cy, xb[NN + i]);
        float dz = __fsub_rn(cz, xb[2*NN + i]);
        float d2 = sqdist3(dx, dy, dz);
        bool in = (d2 <= R2C);
        unsigned long long m = __ballot(in);
        int pos = total + __popcll(m & ((1ull << lane) - 1ull));
        if (in && pos < KK) gout[pos] = i;
        if (firstIdx < 0 && m) firstIdx = base + (__ffsll((unsigned long long)m) - 1);
        total += __popcll(m);
        if (total >= KK) break;
    }
    if (total < KK){
        int f = (total > 0) ? firstIdx : (NN - 1);
        for (int p = total + lane; p < KK; p += 64) gout[p] = f;
    }
}

// ---------- layer0: gather + 67->64 matmul + stats ----------
__global__ __launch_bounds__(256) void l0_kernel(const float* __restrict__ pts_n,
                                                 const float* __restrict__ xyz_n,
                                                 const float* __restrict__ newxyz,
                                                 const int* __restrict__ gidx,
                                                 const float* __restrict__ W0,
                                                 const float* __restrict__ b0,
                                                 uint4* __restrict__ y0,
                                                 float* __restrict__ part0){
    __shared__ float lsum[4][64][2];
    int tid = threadIdx.x;
    int pixel = blockIdx.x * 256 + tid;
    int sample = pixel >> 5;
    int b = sample >> 10;
    int gi = gidx[pixel];
    int wave = tid >> 6, lane = tid & 63;

    float ff[67];
    const float4* prow = (const float4*)(pts_n + ((size_t)b * NN + gi) * 64);
#pragma unroll
    for (int q = 0; q < 16; ++q){
        float4 v = prow[q];
        ff[q*4] = v.x; ff[q*4+1] = v.y; ff[q*4+2] = v.z; ff[q*4+3] = v.w;
    }
    const float* pr = xyz_n + ((size_t)b * NN + gi) * 3;
    const float* nw = newxyz + (size_t)sample * 3;
    ff[64] = __fsub_rn(pr[0], nw[0]) / 0.2f;
    ff[65] = __fsub_rn(pr[1], nw[1]) / 0.2f;
    ff[66] = __fsub_rn(pr[2], nw[2]) / 0.2f;

    for (int oc = 0; oc < 8; ++oc){
        float acc[8];
#pragma unroll
        for (int j = 0; j < 8; ++j) acc[j] = b0[oc*8+j];
#pragma unroll
        for (int c = 0; c < 67; ++c){
            float fe = ff[c];
#pragma unroll
            for (int j = 0; j < 8; ++j) acc[j] += fe * W0[(oc*8+j)*67 + c];
        }
        uint4 pk;
        unsigned us[8];
#pragma unroll
        for (int j = 0; j < 8; ++j){
            float v = acc[j];
            float s1 = v, s2 = v * v;
#pragma unroll
            for (int m = 1; m <= 32; m <<= 1){
                s1 += __shfl_xor(s1, m);
                s2 += __shfl_xor(s2, m);
            }
            if (lane == 0){ lsum[wave][oc*8+j][0] = s1; lsum[wave][oc*8+j][1] = s2; }
            us[j] = f2bf(v);
        }
        pk.x = us[0] | (us[1] << 16);
        pk.y = us[2] | (us[3] << 16);
        pk.z = us[4] | (us[5] << 16);
        pk.w = us[6] | (us[7] << 16);
        y0[(size_t)pixel * 8 + oc] = pk;
    }
    __syncthreads();
    if (tid < 128){
        float s = lsum[0][tid>>1][tid&1] + lsum[1][tid>>1][tid&1]
                + lsum[2][tid>>1][tid&1] + lsum[3][tid>>1][tid&1];
        part0[(size_t)blockIdx.x * 128 + tid] = s;
    }
}

// ---------- layer1: bn+relu + 64->64 matmul + stats ----------
__global__ __launch_bounds__(256) void l1_kernel(const uint4* __restrict__ y0,
                                                 const float* __restrict__ scale0,
                                                 const float* __restrict__ shift0,
                                                 const float* __restrict__ W1,
                                                 const float* __restrict__ b1,
                                                 uint4* __restrict__ y1,
                                                 float* __restrict__ part1){
    __shared__ float lsum[4][64][2];
    int tid = threadIdx.x;
    int pixel = blockIdx.x * 256 + tid;
    int wave = tid >> 6, lane = tid & 63;

    float x[64];
#pragma unroll
    for (int q = 0; q < 8; ++q){
        uint4 v = y0[(size_t)pixel * 8 + q];
        unsigned w[4] = {v.x, v.y, v.z, v.w};
#pragma unroll
        for (int r = 0; r < 4; ++r){
            int c = q*8 + r*2;
            x[c]   = fmaxf(bf2f(w[r] & 0xFFFFu) * scale0[c]   + shift0[c],   0.f);
            x[c+1] = fmaxf(bf2f(w[r] >> 16)     * scale0[c+1] + shift0[c+1], 0.f);
        }
    }
    for (int oc = 0; oc < 8; ++oc){
        float acc[8];
#pragma unroll
        for (int j = 0; j < 8; ++j) acc[j] = b1[oc*8+j];
#pragma unroll
        for (int c = 0; c < 64; ++c){
            float fe = x[c];
#pragma unroll
            for (int j = 0; j < 8; ++j) acc[j] += fe * W1[(oc*8+j)*64 + c];
        }
        uint4 pk;
        unsigned us[8];
#pragma unroll
        for (int j = 0; j < 8; ++j){
            float v = acc[j];
            float s1 = v, s2 = v * v;
#pragma unroll
            for (int m = 1; m <= 32; m <<= 1){
                s1 += __shfl_xor(s1, m);
                s2 += __shfl_xor(s2, m);
            }
            if (lane == 0){ lsum[wave][oc*8+j][0] = s1; lsum[wave][oc*8+j][1] = s2; }
            us[j] = f2bf(v);
        }
        pk.x = us[0] | (us[1] << 16);
        pk.y = us[2] | (us[3] << 16);
        pk.z = us[4] | (us[5] << 16);
        pk.w = us[6] | (us[7] << 16);
        y1[(size_t)pixel * 8 + oc] = pk;
    }
    __syncthreads();
    if (tid < 128){
        float s = lsum[0][tid>>1][tid&1] + lsum[1][tid>>1][tid&1]
                + lsum[2][tid>>1][tid&1] + lsum[3][tid>>1][tid&1];
        part1[(size_t)blockIdx.x * 128 + tid] = s;
    }
}

// ---------- layer2: bn+relu + 64->128 matmul + k-max/min + stats ----------
__global__ __launch_bounds__(256) void l2_kernel(const uint4* __restrict__ y1,
                                                 const float* __restrict__ scale1,
                                                 const float* __restrict__ shift1,
                                                 const float* __restrict__ W2,
                                                 const float* __restrict__ b2,
                                                 float* __restrict__ maxmin,
                                                 float* __restrict__ part2){
    __shared__ float lsum[4][128][2];
    int tid = threadIdx.x;
    int pixel = blockIdx.x * 256 + tid;
    int sample = pixel >> 5;
    int wave = tid >> 6, lane = tid & 63;

    float x[64];
#pragma unroll
    for (int q = 0; q < 8; ++q){
        uint4 v = y1[(size_t)pixel * 8 + q];
        unsigned w[4] = {v.x, v.y, v.z, v.w};
#pragma unroll
        for (int r = 0; r < 4; ++r){
            int c = q*8 + r*2;
            x[c]   = fmaxf(bf2f(w[r] & 0xFFFFu) * scale1[c]   + shift1[c],   0.f);
            x[c+1] = fmaxf(bf2f(w[r] >> 16)     * scale1[c+1] + shift1[c+1], 0.f);
        }
    }
    for (int oc = 0; oc < 16; ++oc){
        float acc[8];
#pragma unroll
        for (int j = 0; j < 8; ++j) acc[j] = b2[oc*8+j];
#pragma unroll
        for (int c = 0; c < 64; ++c){
            float fe = x[c];
#pragma unroll
            for (int j = 0; j < 8; ++j) acc[j] += fe * W2[(oc*8+j)*64 + c];
        }
#pragma unroll
        for (int j = 0; j < 8; ++j){
            float v = acc[j];
            int ch = oc*8 + j;
            float mx = v, mn = v;
#pragma unroll
            for (int m = 1; m <= 16; m <<= 1){
                mx = fmaxf(mx, __shfl_xor(mx, m));
                mn = fminf(mn, __shfl_xor(mn, m));
            }
            float s1 = v, s2 = v * v;
#pragma unroll
            for (int m = 1; m <= 32; m <<= 1){
                s1 += __shfl_xor(s1, m);
                s2 += __shfl_xor(s2, m);
            }
            if (lane == 0){ lsum[wave][ch][0] = s1; lsum[wave][ch][1] = s2; }
            if ((tid & 31) == 0){
                float* mm = maxmin + ((size_t)sample * 128 + ch) * 2;
                mm[0] = mx; mm[1] = mn;
            }
        }
    }
    __syncthreads();
    {
        float s = lsum[0][tid>>1][tid&1] + lsum[1][tid>>1][tid&1]
                + lsum[2][tid>>1][tid&1] + lsum[3][tid>>1][tid&1];
        part2[(size_t)blockIdx.x * 256 + tid] = s;
    }
}

// ---------- finalize BN params (parallel: 1024 threads) ----------
__global__ __launch_bounds__(1024) void fin_kernel(const float* __restrict__ part, int O,
                           const float* __restrict__ g, const float* __restrict__ be,
                           float* __restrict__ scale, float* __restrict__ shift){
    __shared__ float ls[1024];
    __shared__ float tot[256];
    int tid = threadIdx.x;
    int M = 2 * O;               // 128 or 256
    int C = 1024 / M;            // 8 or 4 chunks
    int m = tid & (M - 1);
    int chunk = tid / M;
    int per = 1024 / C;          // blocks per chunk
    float s = 0.f;
    for (int r = 0; r < per; ++r){
        int blk = chunk * per + r;
        s += part[(size_t)blk * M + m];
    }
    ls[tid] = s;
    __syncthreads();
    if (tid < M){
        float tt = 0.f;
        for (int c2 = 0; c2 < C; ++c2) tt += ls[c2 * M + tid];
        tot[tid] = tt;
    }
    __syncthreads();
    if (tid < O){
        float s1 = tot[2*tid], s2 = tot[2*tid+1];
        float inv = 1.0f / (float)NPIX;
        float mu = s1 * inv;
        float var = s2 * inv - mu * mu;
        float rs = 1.0f / sqrtf(var + EPS);
        float sc = rs * g[tid];
        scale[tid] = sc;
        shift[tid] = be[tid] - mu * sc;
    }
}

// ---------- output: apply BN to max/min, relu, transpose write ----------
__global__ __launch_bounds__(256) void out_kernel(const float* __restrict__ maxmin,
                                                  const float* __restrict__ scale2,
                                                  const float* __restrict__ shift2,
                                                  float* __restrict__ out){
    int gid = blockIdx.x * 256 + threadIdx.x;  // 1048576, layout (b,o,s)
    int s = gid & 1023;
    int o = (gid >> 10) & 127;
    int b = gid >> 17;
    int sample = b * 1024 + s;
    float2 mm = ((const float2*)maxmin)[(size_t)sample * 128 + o];
    float sc = scale2[o], sh = shift2[o];
    float v = (sc >= 0.f) ? mm.x : mm.y;
    out[gid] = fmaxf(v * sc + sh, 0.f);
}

extern "C" void kernel_launch(void* const* d_in, const int* in_sizes, int n_in,
                              void* d_out, int out_size, void* d_ws, size_t ws_size,
                              hipStream_t stream) {
    const float* xyz = (const float*)d_in[0];
    const float* pts = (const float*)d_in[1];
    const float* W0 = (const float*)d_in[2];
    const float* b0 = (const float*)d_in[3];
    const float* g0 = (const float*)d_in[4];
    const float* be0 = (const float*)d_in[5];
    const float* W1 = (const float*)d_in[6];
    const float* b1 = (const float*)d_in[7];
    const float* g1 = (const float*)d_in[8];
    const float* be1 = (const float*)d_in[9];
    const float* W2 = (const float*)d_in[10];
    const float* b2 = (const float*)d_in[11];
    const float* g2 = (const float*)d_in[12];
    const float* be2 = (const float*)d_in[13];

    char* ws = (char*)d_ws;
    float* newxyz = (float*)(ws + OFF_NEWXYZ);
    int*   gidx   = (int*)(ws + OFF_GIDX);
    float* xyz_n  = (float*)(ws + OFF_XYZN);
    float* pts_n  = (float*)(ws + OFF_PTSN);
    uint4* y0     = (uint4*)(ws + OFF_Y0);
    uint4* y1     = (uint4*)(ws + OFF_Y1);
    float* maxmin = (float*)(ws + OFF_MAXMIN);
    float* part0  = (float*)(ws + OFF_P0);
    float* part1  = (float*)(ws + OFF_P1);
    float* part2  = (float*)(ws + OFF_P2);
    float* sc     = (float*)(ws + OFF_SC);
    float* scale0 = sc,        *shift0 = sc + 64;
    float* scale1 = sc + 128,  *shift1 = sc + 192;
    float* scale2 = sc + 256,  *shift2 = sc + 384;

    float* out = (float*)d_out;
    float* out_np = out + BB * 3 * SS;

    hipLaunchKernelGGL(t_kernel, dim3(256), dim3(256), 0, stream, xyz, pts, xyz_n, pts_n);
    hipLaunchKernelGGL(fps_kernel, dim3(BB), dim3(FT), 0, stream, xyz, newxyz, out);
    hipLaunchKernelGGL(qb_kernel, dim3(2048), dim3(256), 0, stream, xyz, newxyz, gidx);
    hipLaunchKernelGGL(l0_kernel, dim3(1024), dim3(256), 0, stream,
                       pts_n, xyz_n, newxyz, gidx, W0, b0, y0, part0);
    hipLaunchKernelGGL(fin_kernel, dim3(1), dim3(1024), 0, stream, part0, 64, g0, be0, scale0, shift0);
    hipLaunchKernelGGL(l1_kernel, dim3(1024), dim3(256), 0, stream,
                       y0, scale0, shift0, W1, b1, y1, part1);
    hipLaunchKernelGGL(fin_kernel, dim3(1), dim3(1024), 0, stream, part1, 64, g1, be1, scale1, shift1);
    hipLaunchKernelGGL(l2_kernel, dim3(1024), dim3(256), 0, stream,
                       y1, scale1, shift1, W2, b2, maxmin, part2);
    hipLaunchKernelGGL(fin_kernel, dim3(1), dim3(1024), 0, stream, part2, 128, g2, be2, scale2, shift2);
    hipLaunchKernelGGL(out_kernel, dim3(4096), dim3(256), 0, stream, maxmin, scale2, shift2, out_np);
}

// Round 6
// 1579.349 us; speedup vs baseline: 1.2173x; 1.0987x over previous
//
#include <hip/hip_runtime.h>

#define BB 8
#define NN 8192
#define SS 1024
#define KK 32
#define NPIX (BB*SS*KK)   // 262144
#define R2C 0.04f
#define EPS 1e-5f

#define FT 512            // fps threads
#define FW (FT/64)        // 8 waves
#define PPT (NN/FT)       // 16 points per thread
#define NCELL 4096        // 16^3 morton cells

// ---------- ws layout (bytes) ----------
#define OFF_IDX      0u
#define OFF_NEWXYZ   (OFF_IDX + BB*SS*4)
#define OFF_GIDX     (OFF_NEWXYZ + BB*SS*3*4)
#define OFF_XYZN     (OFF_GIDX + BB*SS*KK*4)
#define OFF_PTSN     (OFF_XYZN + BB*NN*3*4)
#define OFF_Y0       (OFF_PTSN + BB*NN*64*4)
#define OFF_Y1       (OFF_Y0 + NPIX*64*2)
#define OFF_MAXMIN   (OFF_Y1 + NPIX*64*2)
#define OFF_P0       (OFF_MAXMIN + BB*SS*128*2*4)
#define OFF_P1       (OFF_P0 + 1024*128*4)
#define OFF_P2       (OFF_P1 + 1024*128*4)
#define OFF_SC       (OFF_P2 + 1024*256*4)

__device__ __forceinline__ unsigned short f2bf(float x){
    unsigned u = __float_as_uint(x);
    unsigned r = (u + 0x7FFFu + ((u >> 16) & 1u)) >> 16;
    return (unsigned short)r;
}
__device__ __forceinline__ float bf2f(unsigned h){
    return __uint_as_float(h << 16);
}
__device__ __forceinline__ float sqdist3(float dx, float dy, float dz){
    // numpy order, no fma contraction: ((dx*dx)+(dy*dy))+(dz*dz)
    return __fadd_rn(__fadd_rn(__fmul_rn(dx,dx), __fmul_rn(dy,dy)), __fmul_rn(dz,dz));
}
__device__ __forceinline__ int spread4(int v){ // bits 0..3 -> 0,3,6,9
    return (v&1) | ((v&2)<<2) | ((v&4)<<4) | ((v&8)<<6);
}

// DPP u64 max step: VALU-speed cross-lane (no LDS pipe round-trip)
template<int CTRL>
__device__ __forceinline__ unsigned long long dpp_max_step(unsigned long long k){
    int lo = (int)(unsigned)k;
    int hi = (int)(unsigned)(k >> 32);
    int olo = __builtin_amdgcn_update_dpp(0, lo, CTRL, 0xf, 0xf, true);
    int ohi = __builtin_amdgcn_update_dpp(0, hi, CTRL, 0xf, 0xf, true);
    unsigned long long o = ((unsigned long long)(unsigned)ohi << 32) | (unsigned)olo;
    return (o > k) ? o : k;
}
// after this, lane 63 holds the wave-wide max (keys are nonneg, 0 is identity)
__device__ __forceinline__ unsigned long long wave_max_u64(unsigned long long k){
    k = dpp_max_step<0x111>(k); // row_shr:1
    k = dpp_max_step<0x112>(k); // row_shr:2
    k = dpp_max_step<0x114>(k); // row_shr:4
    k = dpp_max_step<0x118>(k); // row_shr:8  -> lane15 of each row = row max
    k = dpp_max_step<0x142>(k); // row_bcast15
    k = dpp_max_step<0x143>(k); // row_bcast31 -> lane63 = full wave max
    return k;
}

// ---------- transpose: xyz (B,3,N)->(B,N,3), pts (B,64,N)->(B,N,64) ----------
__global__ __launch_bounds__(256) void t_kernel(const float* __restrict__ xyz,
                                                const float* __restrict__ pts,
                                                float* __restrict__ xyz_n,
                                                float* __restrict__ pts_n){
    int gid = blockIdx.x * 256 + threadIdx.x;   // 65536 = B*N
    int b = gid >> 13, i = gid & (NN - 1);
    const float* xb = xyz + (size_t)b * 3 * NN;
    float x = xb[i], y = xb[NN + i], z = xb[2 * NN + i];
    float* xd = xyz_n + ((size_t)b * NN + i) * 3;
    xd[0] = x; xd[1] = y; xd[2] = z;
    const float* pb = pts + (size_t)b * 64 * NN + i;
    float4* pd = (float4*)(pts_n + ((size_t)b * NN + i) * 64);
#pragma unroll
    for (int q = 0; q < 16; ++q){
        float4 v;
        v.x = pb[(q*4+0)*NN]; v.y = pb[(q*4+1)*NN];
        v.z = pb[(q*4+2)*NN]; v.w = pb[(q*4+3)*NN];
        pd[q] = v;
    }
}

// ---------- FPS: morton sort + exact bbox prune + DPP + single ds_max cell ----------
__global__ __launch_bounds__(FT) void fps_kernel(const float* __restrict__ xyz,
                                                 float* __restrict__ newxyz,
                                                 float* __restrict__ out){
    __shared__ float sx[NN], sy[NN], sz[NN];     // original-index order
    __shared__ int   si[NN];                     // sorted -> original idx
    __shared__ int   hist[NCELL];                // sort workspace, then winner history
    __shared__ int   waveTot[FW];
    __shared__ unsigned long long cells[4];
    int b = blockIdx.x, tid = threadIdx.x;
    int wave = tid >> 6, lane = tid & 63;
    const float* xb = xyz + (size_t)b * 3 * NN;

    // ---- load coords to LDS (original order) + compute morton cells ----
    int cell[PPT];
#pragma unroll
    for (int j = 0; j < PPT; ++j){
        int i = tid + j * FT;
        float x = xb[i], y = xb[NN + i], z = xb[2*NN + i];
        sx[i] = x; sy[i] = y; sz[i] = z;
        int cx = min(15, max(0, (int)(x * 16.f)));
        int cy = min(15, max(0, (int)(y * 16.f)));
        int cz = min(15, max(0, (int)(z * 16.f)));
        cell[j] = spread4(cx) | (spread4(cy) << 1) | (spread4(cz) << 2);
    }
    // ---- histogram ----
#pragma unroll
    for (int k = 0; k < NCELL/FT; ++k) hist[tid * (NCELL/FT) + k] = 0;
    if (tid < 4) cells[tid] = 0ull;
    __syncthreads();
#pragma unroll
    for (int j = 0; j < PPT; ++j) atomicAdd(&hist[cell[j]], 1);
    __syncthreads();
    // ---- exclusive scan over 4096 cells ----
    {
        int base0 = tid * (NCELL/FT);
        int sum8 = 0;
#pragma unroll
        for (int k = 0; k < NCELL/FT; ++k) sum8 += hist[base0 + k];
        int s = sum8;
#pragma unroll
        for (int m = 1; m < 64; m <<= 1){
            int v = __shfl_up(s, m);
            if (lane >= m) s += v;
        }
        if (lane == 63) waveTot[wave] = s;
        __syncthreads();
        int wbase = 0;
        for (int w2 = 0; w2 < FW; ++w2) if (w2 < wave) wbase += waveTot[w2];
        int run = wbase + s - sum8;
#pragma unroll
        for (int k = 0; k < NCELL/FT; ++k){
            int h = hist[base0 + k];
            hist[base0 + k] = run;
            run += h;
        }
    }
    __syncthreads();
    // ---- scatter permutation ----
#pragma unroll
    for (int j = 0; j < PPT; ++j){
        int pos = atomicAdd(&hist[cell[j]], 1);
        si[pos] = tid + j * FT;
    }
    __syncthreads();
    // ---- gather thread's contiguous sorted chunk + bbox ----
    float px[PPT], py[PPT], pz[PPT], dist[PPT];
    int oi[PPT];
    float bxmin =  1e30f, bxmax = -1e30f;
    float bymin =  1e30f, bymax = -1e30f;
    float bzmin =  1e30f, bzmax = -1e30f;
#pragma unroll
    for (int j = 0; j < PPT; ++j){
        int g = si[tid * PPT + j];
        oi[j] = g;
        float x = sx[g], y = sy[g], z = sz[g];
        px[j] = x; py[j] = y; pz[j] = z;
        bxmin = fminf(bxmin, x); bxmax = fmaxf(bxmax, x);
        bymin = fminf(bymin, y); bymax = fmaxf(bymax, y);
        bzmin = fminf(bzmin, z); bzmax = fmaxf(bzmax, z);
        dist[j] = __int_as_float(0x7f800000); // +inf
    }
    __syncthreads();   // hist[] now dead -> reused as winner history

    unsigned long long mykey = 0ull;      // exact chunk {maxdist, argidx} at all times
    unsigned long long lane63cache = 0ull; // valid in lane 63 only
    float tmax = __int_as_float(0x7f800000);
    int w = 0;
    for (int t = 0; t < SS; ++t){
        // reference semantics: idx[t] = CURRENT point, then compute next argmax
        if (tid == 0) hist[t] = w;
        float lx = sx[w], ly = sy[w], lz = sz[w];
        // exact-safe bbox prune: d_bb <= d_p (f32, same rounding order) for all p in chunk
        float cdx = __fsub_rn(lx, fminf(fmaxf(lx, bxmin), bxmax));
        float cdy = __fsub_rn(ly, fminf(fmaxf(ly, bymin), bymax));
        float cdz = __fsub_rn(lz, fminf(fmaxf(lz, bzmin), bzmax));
        float d_bb = sqdist3(cdx, cdy, cdz);
        bool active = d_bb < tmax;
        unsigned long long bal = __ballot(active);
        if (active){
            {
#pragma clang fp contract(off)
#pragma unroll
                for (int j = 0; j < PPT; ++j){
                    float dx = px[j] - lx;
                    float dy = py[j] - ly;
                    float dz = pz[j] - lz;
                    float d = ((dx*dx) + (dy*dy)) + (dz*dz);
                    dist[j] = fminf(dist[j], d);
                }
            }
            // depth-4 tree max (shorter dep chain than 16-deep scan)
            float m0 = fmaxf(dist[0],  dist[1]);
            float m1 = fmaxf(dist[2],  dist[3]);
            float m2 = fmaxf(dist[4],  dist[5]);
            float m3 = fmaxf(dist[6],  dist[7]);
            float m4 = fmaxf(dist[8],  dist[9]);
            float m5 = fmaxf(dist[10], dist[11]);
            float m6 = fmaxf(dist[12], dist[13]);
            float m7 = fmaxf(dist[14], dist[15]);
            m0 = fmaxf(m0, m1); m2 = fmaxf(m2, m3);
            m4 = fmaxf(m4, m5); m6 = fmaxf(m6, m7);
            m0 = fmaxf(m0, m2); m4 = fmaxf(m4, m6);
            float maxd = fmaxf(m0, m4);
            int bo = 0x7fffffff;
#pragma unroll
            for (int j = 0; j < PPT; ++j)
                if (dist[j] == maxd) bo = min(bo, oi[j]);
            mykey = ((unsigned long long)__float_as_uint(maxd) << 32)
                  | (unsigned)(~bo);
            tmax = maxd;
        }
        if (bal){
            unsigned long long k = wave_max_u64(mykey);
            if (lane == 63) lane63cache = k;
        }
        if (lane == 63) atomicMax(&cells[t & 3], lane63cache);
        if (tid == 0) cells[(t + 2) & 3] = 0ull;   // reset 2 barriers ahead (race-free)
        __syncthreads();
        unsigned long long km = cells[t & 3];
        w = (int)(~(unsigned)km);
    }
    __syncthreads();
    // ---- coalesced writeback from history ----
    for (int t2 = tid; t2 < SS; t2 += FT){
        int hw = hist[t2];
        float x = sx[hw], y = sy[hw], z = sz[hw];
        out[(size_t)b * 3 * SS + t2]          = x;
        out[(size_t)b * 3 * SS + SS + t2]     = y;
        out[(size_t)b * 3 * SS + 2*SS + t2]   = z;
        float* nw = newxyz + ((size_t)b * SS + t2) * 3;
        nw[0] = x; nw[1] = y; nw[2] = z;
    }
}

// ---------- query ball: one wave per sample, planar coalesced reads ----------
__global__ __launch_bounds__(256) void qb_kernel(const float* __restrict__ xyz,
                                                 const float* __restrict__ newxyz,
                                                 int* __restrict__ gidx){
    int wid = (blockIdx.x * 256 + threadIdx.x) >> 6;  // sample id 0..8191
    int lane = threadIdx.x & 63;
    int b = wid >> 10;
    const float* nw = newxyz + (size_t)wid * 3;
    float cx = nw[0], cy = nw[1], cz = nw[2];
    const float* xb = xyz + (size_t)b * 3 * NN;
    int total = 0, firstIdx = -1;
    int* gout = gidx + (size_t)wid * KK;
    for (int base = 0; base < NN; base += 64){
        int i = base + lane;
        float dx = __fsub_rn(cx, xb[i]);
        float dy = __fsub_rn(cy, xb[NN + i]);
        float dz = __fsub_rn(cz, xb[2*NN + i]);
        float d2 = sqdist3(dx, dy, dz);
        bool in = (d2 <= R2C);
        unsigned long long m = __ballot(in);
        int pos = total + __popcll(m & ((1ull << lane) - 1ull));
        if (in && pos < KK) gout[pos] = i;
        if (firstIdx < 0 && m) firstIdx = base + (__ffsll((unsigned long long)m) - 1);
        total += __popcll(m);
        if (total >= KK) break;
    }
    if (total < KK){
        int f = (total > 0) ? firstIdx : (NN - 1);
        for (int p = total + lane; p < KK; p += 64) gout[p] = f;
    }
}

// ---------- layer0: gather + 67->64 matmul + stats ----------
__global__ __launch_bounds__(256) void l0_kernel(const float* __restrict__ pts_n,
                                                 const float* __restrict__ xyz_n,
                                                 const float* __restrict__ newxyz,
                                                 const int* __restrict__ gidx,
                                                 const float* __restrict__ W0,
                                                 const float* __restrict__ b0,
                                                 uint4* __restrict__ y0,
                                                 float* __restrict__ part0){
    __shared__ float lsum[4][64][2];
    int tid = threadIdx.x;
    int pixel = blockIdx.x * 256 + tid;
    int sample = pixel >> 5;
    int b = sample >> 10;
    int gi = gidx[pixel];
    int wave = tid >> 6, lane = tid & 63;

    float ff[67];
    const float4* prow = (const float4*)(pts_n + ((size_t)b * NN + gi) * 64);
#pragma unroll
    for (int q = 0; q < 16; ++q){
        float4 v = prow[q];
        ff[q*4] = v.x; ff[q*4+1] = v.y; ff[q*4+2] = v.z; ff[q*4+3] = v.w;
    }
    const float* pr = xyz_n + ((size_t)b * NN + gi) * 3;
    const float* nw = newxyz + (size_t)sample * 3;
    ff[64] = __fsub_rn(pr[0], nw[0]) / 0.2f;
    ff[65] = __fsub_rn(pr[1], nw[1]) / 0.2f;
    ff[66] = __fsub_rn(pr[2], nw[2]) / 0.2f;

    for (int oc = 0; oc < 8; ++oc){
        float acc[8];
#pragma unroll
        for (int j = 0; j < 8; ++j) acc[j] = b0[oc*8+j];
#pragma unroll
        for (int c = 0; c < 67; ++c){
            float fe = ff[c];
#pragma unroll
            for (int j = 0; j < 8; ++j) acc[j] += fe * W0[(oc*8+j)*67 + c];
        }
        uint4 pk;
        unsigned us[8];
#pragma unroll
        for (int j = 0; j < 8; ++j){
            float v = acc[j];
            float s1 = v, s2 = v * v;
#pragma unroll
            for (int m = 1; m <= 32; m <<= 1){
                s1 += __shfl_xor(s1, m);
                s2 += __shfl_xor(s2, m);
            }
            if (lane == 0){ lsum[wave][oc*8+j][0] = s1; lsum[wave][oc*8+j][1] = s2; }
            us[j] = f2bf(v);
        }
        pk.x = us[0] | (us[1] << 16);
        pk.y = us[2] | (us[3] << 16);
        pk.z = us[4] | (us[5] << 16);
        pk.w = us[6] | (us[7] << 16);
        y0[(size_t)pixel * 8 + oc] = pk;
    }
    __syncthreads();
    if (tid < 128){
        float s = lsum[0][tid>>1][tid&1] + lsum[1][tid>>1][tid&1]
                + lsum[2][tid>>1][tid&1] + lsum[3][tid>>1][tid&1];
        part0[(size_t)blockIdx.x * 128 + tid] = s;
    }
}

// ---------- layer1: bn+relu + 64->64 matmul + stats ----------
__global__ __launch_bounds__(256) void l1_kernel(const uint4* __restrict__ y0,
                                                 const float* __restrict__ scale0,
                                                 const float* __restrict__ shift0,
                                                 const float* __restrict__ W1,
                                                 const float* __restrict__ b1,
                                                 uint4* __restrict__ y1,
                                                 float* __restrict__ part1){
    __shared__ float lsum[4][64][2];
    int tid = threadIdx.x;
    int pixel = blockIdx.x * 256 + tid;
    int wave = tid >> 6, lane = tid & 63;

    float x[64];
#pragma unroll
    for (int q = 0; q < 8; ++q){
        uint4 v = y0[(size_t)pixel * 8 + q];
        unsigned w[4] = {v.x, v.y, v.z, v.w};
#pragma unroll
        for (int r = 0; r < 4; ++r){
            int c = q*8 + r*2;
            x[c]   = fmaxf(bf2f(w[r] & 0xFFFFu) * scale0[c]   + shift0[c],   0.f);
            x[c+1] = fmaxf(bf2f(w[r] >> 16)     * scale0[c+1] + shift0[c+1], 0.f);
        }
    }
    for (int oc = 0; oc < 8; ++oc){
        float acc[8];
#pragma unroll
        for (int j = 0; j < 8; ++j) acc[j] = b1[oc*8+j];
#pragma unroll
        for (int c = 0; c < 64; ++c){
            float fe = x[c];
#pragma unroll
            for (int j = 0; j < 8; ++j) acc[j] += fe * W1[(oc*8+j)*64 + c];
        }
        uint4 pk;
        unsigned us[8];
#pragma unroll
        for (int j = 0; j < 8; ++j){
            float v = acc[j];
            float s1 = v, s2 = v * v;
#pragma unroll
            for (int m = 1; m <= 32; m <<= 1){
                s1 += __shfl_xor(s1, m);
                s2 += __shfl_xor(s2, m);
            }
            if (lane == 0){ lsum[wave][oc*8+j][0] = s1; lsum[wave][oc*8+j][1] = s2; }
            us[j] = f2bf(v);
        }
        pk.x = us[0] | (us[1] << 16);
        pk.y = us[2] | (us[3] << 16);
        pk.z = us[4] | (us[5] << 16);
        pk.w = us[6] | (us[7] << 16);
        y1[(size_t)pixel * 8 + oc] = pk;
    }
    __syncthreads();
    if (tid < 128){
        float s = lsum[0][tid>>1][tid&1] + lsum[1][tid>>1][tid&1]
                + lsum[2][tid>>1][tid&1] + lsum[3][tid>>1][tid&1];
        part1[(size_t)blockIdx.x * 128 + tid] = s;
    }
}

// ---------- layer2: bn+relu + 64->128 matmul + k-max/min + stats ----------
__global__ __launch_bounds__(256) void l2_kernel(const uint4* __restrict__ y1,
                                                 const float* __restrict__ scale1,
                                                 const float* __restrict__ shift1,
                                                 const float* __restrict__ W2,
                                                 const float* __restrict__ b2,
                                                 float* __restrict__ maxmin,
                                                 float* __restrict__ part2){
    __shared__ float lsum[4][128][2];
    int tid = threadIdx.x;
    int pixel = blockIdx.x * 256 + tid;
    int sample = pixel >> 5;
    int wave = tid >> 6, lane = tid & 63;

    float x[64];
#pragma unroll
    for (int q = 0; q < 8; ++q){
        uint4 v = y1[(size_t)pixel * 8 + q];
        unsigned w[4] = {v.x, v.y, v.z, v.w};
#pragma unroll
        for (int r = 0; r < 4; ++r){
            int c = q*8 + r*2;
            x[c]   = fmaxf(bf2f(w[r] & 0xFFFFu) * scale1[c]   + shift1[c],   0.f);
            x[c+1] = fmaxf(bf2f(w[r] >> 16)     * scale1[c+1] + shift1[c+1], 0.f);
        }
    }
    for (int oc = 0; oc < 16; ++oc){
        float acc[8];
#pragma unroll
        for (int j = 0; j < 8; ++j) acc[j] = b2[oc*8+j];
#pragma unroll
        for (int c = 0; c < 64; ++c){
            float fe = x[c];
#pragma unroll
            for (int j = 0; j < 8; ++j) acc[j] += fe * W2[(oc*8+j)*64 + c];
        }
#pragma unroll
        for (int j = 0; j < 8; ++j){
            float v = acc[j];
            int ch = oc*8 + j;
            float mx = v, mn = v;
#pragma unroll
            for (int m = 1; m <= 16; m <<= 1){
                mx = fmaxf(mx, __shfl_xor(mx, m));
                mn = fminf(mn, __shfl_xor(mn, m));
            }
            float s1 = v, s2 = v * v;
#pragma unroll
            for (int m = 1; m <= 32; m <<= 1){
                s1 += __shfl_xor(s1, m);
                s2 += __shfl_xor(s2, m);
            }
            if (lane == 0){ lsum[wave][ch][0] = s1; lsum[wave][ch][1] = s2; }
            if ((tid & 31) == 0){
                float* mm = maxmin + ((size_t)sample * 128 + ch) * 2;
                mm[0] = mx; mm[1] = mn;
            }
        }
    }
    __syncthreads();
    {
        float s = lsum[0][tid>>1][tid&1] + lsum[1][tid>>1][tid&1]
                + lsum[2][tid>>1][tid&1] + lsum[3][tid>>1][tid&1];
        part2[(size_t)blockIdx.x * 256 + tid] = s;
    }
}

// ---------- finalize BN params (parallel: 1024 threads) ----------
__global__ __launch_bounds__(1024) void fin_kernel(const float* __restrict__ part, int O,
                           const float* __restrict__ g, const float* __restrict__ be,
                           float* __restrict__ scale, float* __restrict__ shift){
    __shared__ float ls[1024];
    __shared__ float tot[256];
    int tid = threadIdx.x;
    int M = 2 * O;               // 128 or 256
    int C = 1024 / M;            // 8 or 4 chunks
    int m = tid & (M - 1);
    int chunk = tid / M;
    int per = 1024 / C;          // blocks per chunk
    float s = 0.f;
    for (int r = 0; r < per; ++r){
        int blk = chunk * per + r;
        s += part[(size_t)blk * M + m];
    }
    ls[tid] = s;
    __syncthreads();
    if (tid < M){
        float tt = 0.f;
        for (int c2 = 0; c2 < C; ++c2) tt += ls[c2 * M + tid];
        tot[tid] = tt;
    }
    __syncthreads();
    if (tid < O){
        float s1 = tot[2*tid], s2 = tot[2*tid+1];
        float inv = 1.0f / (float)NPIX;
        float mu = s1 * inv;
        float var = s2 * inv - mu * mu;
        float rs = 1.0f / sqrtf(var + EPS);
        float sc = rs * g[tid];
        scale[tid] = sc;
        shift[tid] = be[tid] - mu * sc;
    }
}

// ---------- output: apply BN to max/min, relu, transpose write ----------
__global__ __launch_bounds__(256) void out_kernel(const float* __restrict__ maxmin,
                                                  const float* __restrict__ scale2,
                                                  const float* __restrict__ shift2,
                                                  float* __restrict__ out){
    int gid = blockIdx.x * 256 + threadIdx.x;  // 1048576, layout (b,o,s)
    int s = gid & 1023;
    int o = (gid >> 10) & 127;
    int b = gid >> 17;
    int sample = b * 1024 + s;
    float2 mm = ((const float2*)maxmin)[(size_t)sample * 128 + o];
    float sc = scale2[o], sh = shift2[o];
    float v = (sc >= 0.f) ? mm.x : mm.y;
    out[gid] = fmaxf(v * sc + sh, 0.f);
}

extern "C" void kernel_launch(void* const* d_in, const int* in_sizes, int n_in,
                              void* d_out, int out_size, void* d_ws, size_t ws_size,
                              hipStream_t stream) {
    const float* xyz = (const float*)d_in[0];
    const float* pts = (const float*)d_in[1];
    const float* W0 = (const float*)d_in[2];
    const float* b0 = (const float*)d_in[3];
    const float* g0 = (const float*)d_in[4];
    const float* be0 = (const float*)d_in[5];
    const float* W1 = (const float*)d_in[6];
    const float* b1 = (const float*)d_in[7];
    const float* g1 = (const float*)d_in[8];
    const float* be1 = (const float*)d_in[9];
    const float* W2 = (const float*)d_in[10];
    const float* b2 = (const float*)d_in[11];
    const float* g2 = (const float*)d_in[12];
    const float* be2 = (const float*)d_in[13];

    char* ws = (char*)d_ws;
    float* newxyz = (float*)(ws + OFF_NEWXYZ);
    int*   gidx   = (int*)(ws + OFF_GIDX);
    float* xyz_n  = (float*)(ws + OFF_XYZN);
    float* pts_n  = (float*)(ws + OFF_PTSN);
    uint4* y0     = (uint4*)(ws + OFF_Y0);
    uint4* y1     = (uint4*)(ws + OFF_Y1);
    float* maxmin = (float*)(ws + OFF_MAXMIN);
    float* part0  = (float*)(ws + OFF_P0);
    float* part1  = (float*)(ws + OFF_P1);
    float* part2  = (float*)(ws + OFF_P2);
    float* sc     = (float*)(ws + OFF_SC);
    float* scale0 = sc,        *shift0 = sc + 64;
    float* scale1 = sc + 128,  *shift1 = sc + 192;
    float* scale2 = sc + 256,  *shift2 = sc + 384;

    float* out = (float*)d_out;
    float* out_np = out + BB * 3 * SS;

    hipLaunchKernelGGL(t_kernel, dim3(256), dim3(256), 0, stream, xyz, pts, xyz_n, pts_n);
    hipLaunchKernelGGL(fps_kernel, dim3(BB), dim3(FT), 0, stream, xyz, newxyz, out);
    hipLaunchKernelGGL(qb_kernel, dim3(2048), dim3(256), 0, stream, xyz, newxyz, gidx);
    hipLaunchKernelGGL(l0_kernel, dim3(1024), dim3(256), 0, stream,
                       pts_n, xyz_n, newxyz, gidx, W0, b0, y0, part0);
    hipLaunchKernelGGL(fin_kernel, dim3(1), dim3(1024), 0, stream, part0, 64, g0, be0, scale0, shift0);
    hipLaunchKernelGGL(l1_kernel, dim3(1024), dim3(256), 0, stream,
                       y0, scale0, shift0, W1, b1, y1, part1);
    hipLaunchKernelGGL(fin_kernel, dim3(1), dim3(1024), 0, stream, part1, 64, g1, be1, scale1, shift1);
    hipLaunchKernelGGL(l2_kernel, dim3(1024), dim3(256), 0, stream,
                       y1, scale1, shift1, W2, b2, maxmin, part2);
    hipLaunchKernelGGL(fin_kernel, dim3(1), dim3(1024), 0, stream, part2, 128, g2, be2, scale2, shift2);
    hipLaunchKernelGGL(out_kernel, dim3(4096), dim3(256), 0, stream, maxmin, scale2, shift2, out_np);
}

// Round 7
// 1375.324 us; speedup vs baseline: 1.3979x; 1.1483x over previous
//
#include <hip/hip_runtime.h>

#define BB 8
#define NN 8192
#define SS 1024
#define KK 32
#define NPIX (BB*SS*KK)   // 262144
#define R2C 0.04f
#define EPS 1e-5f

#define FT 1024           // fps threads (16 waves)
#define FW (FT/64)        // 16 waves
#define PPT (NN/FT)       // 8 points per thread  -> arrays fit registers, no scratch
#define NCELL 4096        // 16^3 morton cells

// ---------- ws layout (bytes) ----------
#define OFF_IDX      0u
#define OFF_NEWXYZ   (OFF_IDX + BB*SS*4)
#define OFF_GIDX     (OFF_NEWXYZ + BB*SS*3*4)
#define OFF_XYZN     (OFF_GIDX + BB*SS*KK*4)
#define OFF_PTSN     (OFF_XYZN + BB*NN*3*4)
#define OFF_Y0       (OFF_PTSN + BB*NN*64*4)
#define OFF_Y1       (OFF_Y0 + NPIX*64*2)
#define OFF_MAXMIN   (OFF_Y1 + NPIX*64*2)
#define OFF_P0       (OFF_MAXMIN + BB*SS*128*2*4)
#define OFF_P1       (OFF_P0 + 1024*128*4)
#define OFF_P2       (OFF_P1 + 1024*128*4)
#define OFF_SC       (OFF_P2 + 1024*256*4)

__device__ __forceinline__ unsigned short f2bf(float x){
    unsigned u = __float_as_uint(x);
    unsigned r = (u + 0x7FFFu + ((u >> 16) & 1u)) >> 16;
    return (unsigned short)r;
}
__device__ __forceinline__ float bf2f(unsigned h){
    return __uint_as_float(h << 16);
}
__device__ __forceinline__ float sqdist3(float dx, float dy, float dz){
    // numpy order, no fma contraction: ((dx*dx)+(dy*dy))+(dz*dz)
    return __fadd_rn(__fadd_rn(__fmul_rn(dx,dx), __fmul_rn(dy,dy)), __fmul_rn(dz,dz));
}
__device__ __forceinline__ int spread4(int v){ // bits 0..3 -> 0,3,6,9
    return (v&1) | ((v&2)<<2) | ((v&4)<<4) | ((v&8)<<6);
}

// DPP u64 max step: VALU-speed cross-lane (no LDS pipe round-trip)
template<int CTRL>
__device__ __forceinline__ unsigned long long dpp_max_step(unsigned long long k){
    int lo = (int)(unsigned)k;
    int hi = (int)(unsigned)(k >> 32);
    int olo = __builtin_amdgcn_update_dpp(0, lo, CTRL, 0xf, 0xf, true);
    int ohi = __builtin_amdgcn_update_dpp(0, hi, CTRL, 0xf, 0xf, true);
    unsigned long long o = ((unsigned long long)(unsigned)ohi << 32) | (unsigned)olo;
    return (o > k) ? o : k;
}
// after this, lane 63 holds the wave-wide max (keys are nonneg, 0 is identity)
__device__ __forceinline__ unsigned long long wave_max_u64(unsigned long long k){
    k = dpp_max_step<0x111>(k); // row_shr:1
    k = dpp_max_step<0x112>(k); // row_shr:2
    k = dpp_max_step<0x114>(k); // row_shr:4
    k = dpp_max_step<0x118>(k); // row_shr:8  -> lane15 of each row = row max
    k = dpp_max_step<0x142>(k); // row_bcast15
    k = dpp_max_step<0x143>(k); // row_bcast31 -> lane63 = full wave max
    return k;
}

// ---------- transpose: xyz (B,3,N)->(B,N,3), pts (B,64,N)->(B,N,64) ----------
__global__ __launch_bounds__(256) void t_kernel(const float* __restrict__ xyz,
                                                const float* __restrict__ pts,
                                                float* __restrict__ xyz_n,
                                                float* __restrict__ pts_n){
    int gid = blockIdx.x * 256 + threadIdx.x;   // 65536 = B*N
    int b = gid >> 13, i = gid & (NN - 1);
    const float* xb = xyz + (size_t)b * 3 * NN;
    float x = xb[i], y = xb[NN + i], z = xb[2 * NN + i];
    float* xd = xyz_n + ((size_t)b * NN + i) * 3;
    xd[0] = x; xd[1] = y; xd[2] = z;
    const float* pb = pts + (size_t)b * 64 * NN + i;
    float4* pd = (float4*)(pts_n + ((size_t)b * NN + i) * 64);
#pragma unroll
    for (int q = 0; q < 16; ++q){
        float4 v;
        v.x = pb[(q*4+0)*NN]; v.y = pb[(q*4+1)*NN];
        v.z = pb[(q*4+2)*NN]; v.w = pb[(q*4+3)*NN];
        pd[q] = v;
    }
}

// ---------- FPS: morton sort + exact bbox prune + DPP + single ds_max cell ----------
__global__ __launch_bounds__(FT) void fps_kernel(const float* __restrict__ xyz,
                                                 float* __restrict__ newxyz,
                                                 float* __restrict__ out){
    __shared__ float sx[NN], sy[NN], sz[NN];     // original-index order
    __shared__ int   si[NN];                     // sorted -> original idx
    __shared__ int   hist[NCELL];                // sort workspace, then winner history
    __shared__ int   waveTot[FW];
    __shared__ unsigned long long cells[4];
    int b = blockIdx.x, tid = threadIdx.x;
    int wave = tid >> 6, lane = tid & 63;
    const float* xb = xyz + (size_t)b * 3 * NN;

    // ---- load coords to LDS (original order) + compute morton cells ----
    int cell[PPT];
#pragma unroll
    for (int j = 0; j < PPT; ++j){
        int i = tid + j * FT;
        float x = xb[i], y = xb[NN + i], z = xb[2*NN + i];
        sx[i] = x; sy[i] = y; sz[i] = z;
        int cx = min(15, max(0, (int)(x * 16.f)));
        int cy = min(15, max(0, (int)(y * 16.f)));
        int cz = min(15, max(0, (int)(z * 16.f)));
        cell[j] = spread4(cx) | (spread4(cy) << 1) | (spread4(cz) << 2);
    }
    // ---- histogram ----
#pragma unroll
    for (int k = 0; k < NCELL/FT; ++k) hist[tid * (NCELL/FT) + k] = 0;
    if (tid < 4) cells[tid] = 0ull;
    __syncthreads();
#pragma unroll
    for (int j = 0; j < PPT; ++j) atomicAdd(&hist[cell[j]], 1);
    __syncthreads();
    // ---- exclusive scan over 4096 cells ----
    {
        int base0 = tid * (NCELL/FT);
        int sum4 = 0;
#pragma unroll
        for (int k = 0; k < NCELL/FT; ++k) sum4 += hist[base0 + k];
        int s = sum4;
#pragma unroll
        for (int m = 1; m < 64; m <<= 1){
            int v = __shfl_up(s, m);
            if (lane >= m) s += v;
        }
        if (lane == 63) waveTot[wave] = s;
        __syncthreads();
        int wbase = 0;
#pragma unroll
        for (int w2 = 0; w2 < FW; ++w2) if (w2 < wave) wbase += waveTot[w2];
        int run = wbase + s - sum4;
#pragma unroll
        for (int k = 0; k < NCELL/FT; ++k){
            int h = hist[base0 + k];
            hist[base0 + k] = run;
            run += h;
        }
    }
    __syncthreads();
    // ---- scatter permutation ----
#pragma unroll
    for (int j = 0; j < PPT; ++j){
        int pos = atomicAdd(&hist[cell[j]], 1);
        si[pos] = tid + j * FT;
    }
    __syncthreads();
    // ---- gather thread's contiguous sorted chunk + bbox (8 pts -> regs, no spill) ----
    float px[PPT], py[PPT], pz[PPT], dist[PPT];
    int oi[PPT];
    float bxmin =  1e30f, bxmax = -1e30f;
    float bymin =  1e30f, bymax = -1e30f;
    float bzmin =  1e30f, bzmax = -1e30f;
#pragma unroll
    for (int j = 0; j < PPT; ++j){
        int g = si[tid * PPT + j];
        oi[j] = g;
        float x = sx[g], y = sy[g], z = sz[g];
        px[j] = x; py[j] = y; pz[j] = z;
        bxmin = fminf(bxmin, x); bxmax = fmaxf(bxmax, x);
        bymin = fminf(bymin, y); bymax = fmaxf(bymax, y);
        bzmin = fminf(bzmin, z); bzmax = fmaxf(bzmax, z);
        dist[j] = __int_as_float(0x7f800000); // +inf
    }
    __syncthreads();   // hist[] now dead -> reused as winner history

    unsigned long long mykey = 0ull;      // exact chunk {maxdist, argidx} at all times
    unsigned long long lane63cache = 0ull; // valid in lane 63 only
    float tmax = __int_as_float(0x7f800000);
    int w = 0;
    for (int t = 0; t < SS; ++t){
        // reference semantics: idx[t] = CURRENT point, then compute next argmax
        if (tid == 0) hist[t] = w;
        float lx = sx[w], ly = sy[w], lz = sz[w];
        // exact-safe bbox prune: d_bb <= d_p (f32, same rounding order) for all p in chunk
        float cdx = __fsub_rn(lx, fminf(fmaxf(lx, bxmin), bxmax));
        float cdy = __fsub_rn(ly, fminf(fmaxf(ly, bymin), bymax));
        float cdz = __fsub_rn(lz, fminf(fmaxf(lz, bzmin), bzmax));
        float d_bb = sqdist3(cdx, cdy, cdz);
        bool active = d_bb < tmax;
        unsigned long long bal = __ballot(active);
        if (active){
            {
#pragma clang fp contract(off)
#pragma unroll
                for (int j = 0; j < PPT; ++j){
                    float dx = px[j] - lx;
                    float dy = py[j] - ly;
                    float dz = pz[j] - lz;
                    float d = ((dx*dx) + (dy*dy)) + (dz*dz);
                    dist[j] = fminf(dist[j], d);
                }
            }
            // depth-3 tree max
            float m0 = fmaxf(dist[0], dist[1]);
            float m1 = fmaxf(dist[2], dist[3]);
            float m2 = fmaxf(dist[4], dist[5]);
            float m3 = fmaxf(dist[6], dist[7]);
            m0 = fmaxf(m0, m1); m2 = fmaxf(m2, m3);
            float maxd = fmaxf(m0, m2);
            int bo = 0x7fffffff;
#pragma unroll
            for (int j = 0; j < PPT; ++j)
                if (dist[j] == maxd) bo = min(bo, oi[j]);
            mykey = ((unsigned long long)__float_as_uint(maxd) << 32)
                  | (unsigned)(~bo);
            tmax = maxd;
        }
        if (bal){
            unsigned long long k = wave_max_u64(mykey);
            if (lane == 63) lane63cache = k;
        }
        if (lane == 63) atomicMax(&cells[t & 3], lane63cache);
        if (tid == 0) cells[(t + 2) & 3] = 0ull;   // reset 2 barriers ahead (race-free)
        __syncthreads();
        unsigned long long km = cells[t & 3];
        w = (int)(~(unsigned)km);
    }
    __syncthreads();
    // ---- coalesced writeback from history ----
    for (int t2 = tid; t2 < SS; t2 += FT){
        int hw = hist[t2];
        float x = sx[hw], y = sy[hw], z = sz[hw];
        out[(size_t)b * 3 * SS + t2]          = x;
        out[(size_t)b * 3 * SS + SS + t2]     = y;
        out[(size_t)b * 3 * SS + 2*SS + t2]   = z;
        float* nw = newxyz + ((size_t)b * SS + t2) * 3;
        nw[0] = x; nw[1] = y; nw[2] = z;
    }
}

// ---------- query ball: one wave per sample, planar coalesced reads ----------
__global__ __launch_bounds__(256) void qb_kernel(const float* __restrict__ xyz,
                                                 const float* __restrict__ newxyz,
                                                 int* __restrict__ gidx){
    int wid = (blockIdx.x * 256 + threadIdx.x) >> 6;  // sample id 0..8191
    int lane = threadIdx.x & 63;
    int b = wid >> 10;
    const float* nw = newxyz + (size_t)wid * 3;
    float cx = nw[0], cy = nw[1], cz = nw[2];
    const float* xb = xyz + (size_t)b * 3 * NN;
    int total = 0, firstIdx = -1;
    int* gout = gidx + (size_t)wid * KK;
    for (int base = 0; base < NN; base += 64){
        int i = base + lane;
        float dx = __fsub_rn(cx, xb[i]);
        float dy = __fsub_rn(cy, xb[NN + i]);
        float dz = __fsub_rn(cz, xb[2*NN + i]);
        float d2 = sqdist3(dx, dy, dz);
        bool in = (d2 <= R2C);
        unsigned long long m = __ballot(in);
        int pos = total + __popcll(m & ((1ull << lane) - 1ull));
        if (in && pos < KK) gout[pos] = i;
        if (firstIdx < 0 && m) firstIdx = base + (__ffsll((unsigned long long)m) - 1);
        total += __popcll(m);
        if (total >= KK) break;
    }
    if (total < KK){
        int f = (total > 0) ? firstIdx : (NN - 1);
        for (int p = total + lane; p < KK; p += 64) gout[p] = f;
    }
}

// ---------- layer0: gather + 67->64 matmul + stats ----------
__global__ __launch_bounds__(256) void l0_kernel(const float* __restrict__ pts_n,
                                                 const float* __restrict__ xyz_n,
                                                 const float* __restrict__ newxyz,
                                                 const int* __restrict__ gidx,
                                                 const float* __restrict__ W0,
                                                 const float* __restrict__ b0,
                                                 uint4* __restrict__ y0,
                                                 float* __restrict__ part0){
    __shared__ float lsum[4][64][2];
    int tid = threadIdx.x;
    int pixel = blockIdx.x * 256 + tid;
    int sample = pixel >> 5;
    int b = sample >> 10;
    int gi = gidx[pixel];
    int wave = tid >> 6, lane = tid & 63;

    float ff[67];
    const float4* prow = (const float4*)(pts_n + ((size_t)b * NN + gi) * 64);
#pragma unroll
    for (int q = 0; q < 16; ++q){
        float4 v = prow[q];
        ff[q*4] = v.x; ff[q*4+1] = v.y; ff[q*4+2] = v.z; ff[q*4+3] = v.w;
    }
    const float* pr = xyz_n + ((size_t)b * NN + gi) * 3;
    const float* nw = newxyz + (size_t)sample * 3;
    ff[64] = __fsub_rn(pr[0], nw[0]) / 0.2f;
    ff[65] = __fsub_rn(pr[1], nw[1]) / 0.2f;
    ff[66] = __fsub_rn(pr[2], nw[2]) / 0.2f;

    for (int oc = 0; oc < 8; ++oc){
        float acc[8];
#pragma unroll
        for (int j = 0; j < 8; ++j) acc[j] = b0[oc*8+j];
#pragma unroll
        for (int c = 0; c < 67; ++c){
            float fe = ff[c];
#pragma unroll
            for (int j = 0; j < 8; ++j) acc[j] += fe * W0[(oc*8+j)*67 + c];
        }
        uint4 pk;
        unsigned us[8];
#pragma unroll
        for (int j = 0; j < 8; ++j){
            float v = acc[j];
            float s1 = v, s2 = v * v;
#pragma unroll
            for (int m = 1; m <= 32; m <<= 1){
                s1 += __shfl_xor(s1, m);
                s2 += __shfl_xor(s2, m);
            }
            if (lane == 0){ lsum[wave][oc*8+j][0] = s1; lsum[wave][oc*8+j][1] = s2; }
            us[j] = f2bf(v);
        }
        pk.x = us[0] | (us[1] << 16);
        pk.y = us[2] | (us[3] << 16);
        pk.z = us[4] | (us[5] << 16);
        pk.w = us[6] | (us[7] << 16);
        y0[(size_t)pixel * 8 + oc] = pk;
    }
    __syncthreads();
    if (tid < 128){
        float s = lsum[0][tid>>1][tid&1] + lsum[1][tid>>1][tid&1]
                + lsum[2][tid>>1][tid&1] + lsum[3][tid>>1][tid&1];
        part0[(size_t)blockIdx.x * 128 + tid] = s;
    }
}

// ---------- layer1: bn+relu + 64->64 matmul + stats ----------
__global__ __launch_bounds__(256) void l1_kernel(const uint4* __restrict__ y0,
                                                 const float* __restrict__ scale0,
                                                 const float* __restrict__ shift0,
                                                 const float* __restrict__ W1,
                                                 const float* __restrict__ b1,
                                                 uint4* __restrict__ y1,
                                                 float* __restrict__ part1){
    __shared__ float lsum[4][64][2];
    int tid = threadIdx.x;
    int pixel = blockIdx.x * 256 + tid;
    int wave = tid >> 6, lane = tid & 63;

    float x[64];
#pragma unroll
    for (int q = 0; q < 8; ++q){
        uint4 v = y0[(size_t)pixel * 8 + q];
        unsigned w[4] = {v.x, v.y, v.z, v.w};
#pragma unroll
        for (int r = 0; r < 4; ++r){
            int c = q*8 + r*2;
            x[c]   = fmaxf(bf2f(w[r] & 0xFFFFu) * scale0[c]   + shift0[c],   0.f);
            x[c+1] = fmaxf(bf2f(w[r] >> 16)     * scale0[c+1] + shift0[c+1], 0.f);
        }
    }
    for (int oc = 0; oc < 8; ++oc){
        float acc[8];
#pragma unroll
        for (int j = 0; j < 8; ++j) acc[j] = b1[oc*8+j];
#pragma unroll
        for (int c = 0; c < 64; ++c){
            float fe = x[c];
#pragma unroll
            for (int j = 0; j < 8; ++j) acc[j] += fe * W1[(oc*8+j)*64 + c];
        }
        uint4 pk;
        unsigned us[8];
#pragma unroll
        for (int j = 0; j < 8; ++j){
            float v = acc[j];
            float s1 = v, s2 = v * v;
#pragma unroll
            for (int m = 1; m <= 32; m <<= 1){
                s1 += __shfl_xor(s1, m);
                s2 += __shfl_xor(s2, m);
            }
            if (lane == 0){ lsum[wave][oc*8+j][0] = s1; lsum[wave][oc*8+j][1] = s2; }
            us[j] = f2bf(v);
        }
        pk.x = us[0] | (us[1] << 16);
        pk.y = us[2] | (us[3] << 16);
        pk.z = us[4] | (us[5] << 16);
        pk.w = us[6] | (us[7] << 16);
        y1[(size_t)pixel * 8 + oc] = pk;
    }
    __syncthreads();
    if (tid < 128){
        float s = lsum[0][tid>>1][tid&1] + lsum[1][tid>>1][tid&1]
                + lsum[2][tid>>1][tid&1] + lsum[3][tid>>1][tid&1];
        part1[(size_t)blockIdx.x * 128 + tid] = s;
    }
}

// ---------- layer2: bn+relu + 64->128 matmul + k-max/min + stats ----------
__global__ __launch_bounds__(256) void l2_kernel(const uint4* __restrict__ y1,
                                                 const float* __restrict__ scale1,
                                                 const float* __restrict__ shift1,
                                                 const float* __restrict__ W2,
                                                 const float* __restrict__ b2,
                                                 float* __restrict__ maxmin,
                                                 float* __restrict__ part2){
    __shared__ float lsum[4][128][2];
    int tid = threadIdx.x;
    int pixel = blockIdx.x * 256 + tid;
    int sample = pixel >> 5;
    int wave = tid >> 6, lane = tid & 63;

    float x[64];
#pragma unroll
    for (int q = 0; q < 8; ++q){
        uint4 v = y1[(size_t)pixel * 8 + q];
        unsigned w[4] = {v.x, v.y, v.z, v.w};
#pragma unroll
        for (int r = 0; r < 4; ++r){
            int c = q*8 + r*2;
            x[c]   = fmaxf(bf2f(w[r] & 0xFFFFu) * scale1[c]   + shift1[c],   0.f);
            x[c+1] = fmaxf(bf2f(w[r] >> 16)     * scale1[c+1] + shift1[c+1], 0.f);
        }
    }
    for (int oc = 0; oc < 16; ++oc){
        float acc[8];
#pragma unroll
        for (int j = 0; j < 8; ++j) acc[j] = b2[oc*8+j];
#pragma unroll
        for (int c = 0; c < 64; ++c){
            float fe = x[c];
#pragma unroll
            for (int j = 0; j < 8; ++j) acc[j] += fe * W2[(oc*8+j)*64 + c];
        }
#pragma unroll
        for (int j = 0; j < 8; ++j){
            float v = acc[j];
            int ch = oc*8 + j;
            float mx = v, mn = v;
#pragma unroll
            for (int m = 1; m <= 16; m <<= 1){
                mx = fmaxf(mx, __shfl_xor(mx, m));
                mn = fminf(mn, __shfl_xor(mn, m));
            }
            float s1 = v, s2 = v * v;
#pragma unroll
            for (int m = 1; m <= 32; m <<= 1){
                s1 += __shfl_xor(s1, m);
                s2 += __shfl_xor(s2, m);
            }
            if (lane == 0){ lsum[wave][ch][0] = s1; lsum[wave][ch][1] = s2; }
            if ((tid & 31) == 0){
                float* mm = maxmin + ((size_t)sample * 128 + ch) * 2;
                mm[0] = mx; mm[1] = mn;
            }
        }
    }
    __syncthreads();
    {
        float s = lsum[0][tid>>1][tid&1] + lsum[1][tid>>1][tid&1]
                + lsum[2][tid>>1][tid&1] + lsum[3][tid>>1][tid&1];
        part2[(size_t)blockIdx.x * 256 + tid] = s;
    }
}

// ---------- finalize BN params (parallel: 1024 threads) ----------
__global__ __launch_bounds__(1024) void fin_kernel(const float* __restrict__ part, int O,
                           const float* __restrict__ g, const float* __restrict__ be,
                           float* __restrict__ scale, float* __restrict__ shift){
    __shared__ float ls[1024];
    __shared__ float tot[256];
    int tid = threadIdx.x;
    int M = 2 * O;               // 128 or 256
    int C = 1024 / M;            // 8 or 4 chunks
    int m = tid & (M - 1);
    int chunk = tid / M;
    int per = 1024 / C;          // blocks per chunk
    float s = 0.f;
    for (int r = 0; r < per; ++r){
        int blk = chunk * per + r;
        s += part[(size_t)blk * M + m];
    }
    ls[tid] = s;
    __syncthreads();
    if (tid < M){
        float tt = 0.f;
        for (int c2 = 0; c2 < C; ++c2) tt += ls[c2 * M + tid];
        tot[tid] = tt;
    }
    __syncthreads();
    if (tid < O){
        float s1 = tot[2*tid], s2 = tot[2*tid+1];
        float inv = 1.0f / (float)NPIX;
        float mu = s1 * inv;
        float var = s2 * inv - mu * mu;
        float rs = 1.0f / sqrtf(var + EPS);
        float sc = rs * g[tid];
        scale[tid] = sc;
        shift[tid] = be[tid] - mu * sc;
    }
}

// ---------- output: apply BN to max/min, relu, transpose write ----------
__global__ __launch_bounds__(256) void out_kernel(const float* __restrict__ maxmin,
                                                  const float* __restrict__ scale2,
                                                  const float* __restrict__ shift2,
                                                  float* __restrict__ out){
    int gid = blockIdx.x * 256 + threadIdx.x;  // 1048576, layout (b,o,s)
    int s = gid & 1023;
    int o = (gid >> 10) & 127;
    int b = gid >> 17;
    int sample = b * 1024 + s;
    float2 mm = ((const float2*)maxmin)[(size_t)sample * 128 + o];
    float sc = scale2[o], sh = shift2[o];
    float v = (sc >= 0.f) ? mm.x : mm.y;
    out[gid] = fmaxf(v * sc + sh, 0.f);
}

extern "C" void kernel_launch(void* const* d_in, const int* in_sizes, int n_in,
                              void* d_out, int out_size, void* d_ws, size_t ws_size,
                              hipStream_t stream) {
    const float* xyz = (const float*)d_in[0];
    const float* pts = (const float*)d_in[1];
    const float* W0 = (const float*)d_in[2];
    const float* b0 = (const float*)d_in[3];
    const float* g0 = (const float*)d_in[4];
    const float* be0 = (const float*)d_in[5];
    const float* W1 = (const float*)d_in[6];
    const float* b1 = (const float*)d_in[7];
    const float* g1 = (const float*)d_in[8];
    const float* be1 = (const float*)d_in[9];
    const float* W2 = (const float*)d_in[10];
    const float* b2 = (const float*)d_in[11];
    const float* g2 = (const float*)d_in[12];
    const float* be2 = (const float*)d_in[13];

    char* ws = (char*)d_ws;
    float* newxyz = (float*)(ws + OFF_NEWXYZ);
    int*   gidx   = (int*)(ws + OFF_GIDX);
    float* xyz_n  = (float*)(ws + OFF_XYZN);
    float* pts_n  = (float*)(ws + OFF_PTSN);
    uint4* y0     = (uint4*)(ws + OFF_Y0);
    uint4* y1     = (uint4*)(ws + OFF_Y1);
    float* maxmin = (float*)(ws + OFF_MAXMIN);
    float* part0  = (float*)(ws + OFF_P0);
    float* part1  = (float*)(ws + OFF_P1);
    float* part2  = (float*)(ws + OFF_P2);
    float* sc     = (float*)(ws + OFF_SC);
    float* scale0 = sc,        *shift0 = sc + 64;
    float* scale1 = sc + 128,  *shift1 = sc + 192;
    float* scale2 = sc + 256,  *shift2 = sc + 384;

    float* out = (float*)d_out;
    float* out_np = out + BB * 3 * SS;

    hipLaunchKernelGGL(t_kernel, dim3(256), dim3(256), 0, stream, xyz, pts, xyz_n, pts_n);
    hipLaunchKernelGGL(fps_kernel, dim3(BB), dim3(FT), 0, stream, xyz, newxyz, out);
    hipLaunchKernelGGL(qb_kernel, dim3(2048), dim3(256), 0, stream, xyz, newxyz, gidx);
    hipLaunchKernelGGL(l0_kernel, dim3(1024), dim3(256), 0, stream,
                       pts_n, xyz_n, newxyz, gidx, W0, b0, y0, part0);
    hipLaunchKernelGGL(fin_kernel, dim3(1), dim3(1024), 0, stream, part0, 64, g0, be0, scale0, shift0);
    hipLaunchKernelGGL(l1_kernel, dim3(1024), dim3(256), 0, stream,
                       y0, scale0, shift0, W1, b1, y1, part1);
    hipLaunchKernelGGL(fin_kernel, dim3(1), dim3(1024), 0, stream, part1, 64, g1, be1, scale1, shift1);
    hipLaunchKernelGGL(l2_kernel, dim3(1024), dim3(256), 0, stream,
                       y1, scale1, shift1, W2, b2, maxmin, part2);
    hipLaunchKernelGGL(fin_kernel, dim3(1), dim3(1024), 0, stream, part2, 128, g2, be2, scale2, shift2);
    hipLaunchKernelGGL(out_kernel, dim3(4096), dim3(256), 0, stream, maxmin, scale2, shift2, out_np);
}

// Round 8
// 1241.300 us; speedup vs baseline: 1.5488x; 1.1080x over previous
//
#include <hip/hip_runtime.h>

#define BB 8
#define NN 8192
#define SS 1024
#define KK 32
#define NPIX (BB*SS*KK)   // 262144
#define R2C 0.04f
#define EPS 1e-5f

#define FT 1024           // fps threads (16 waves)
#define FW (FT/64)        // 16 waves
#define PPT (NN/FT)       // 8 points per thread  -> arrays fit registers, no scratch
#define NCELL 4096        // 16^3 morton cells
#define TBLK 64           // transpose blocks fused into fps launch

// ---------- ws layout (bytes) ----------
#define OFF_IDX      0u
#define OFF_NEWXYZ   (OFF_IDX + BB*SS*4)
#define OFF_GIDX     (OFF_NEWXYZ + BB*SS*3*4)
#define OFF_XYZN     (OFF_GIDX + BB*SS*KK*4)
#define OFF_PTSN     (OFF_XYZN + BB*NN*3*4)
#define OFF_Y0       (OFF_PTSN + BB*NN*64*4)
#define OFF_Y1       (OFF_Y0 + NPIX*64*2)
#define OFF_MAXMIN   (OFF_Y1 + NPIX*64*2)
#define OFF_P0       (OFF_MAXMIN + BB*SS*128*2*4)
#define OFF_P1       (OFF_P0 + 1024*128*4)
#define OFF_P2       (OFF_P1 + 1024*128*4)
#define OFF_SC       (OFF_P2 + 1024*256*4)

__device__ __forceinline__ unsigned short f2bf(float x){
    unsigned u = __float_as_uint(x);
    unsigned r = (u + 0x7FFFu + ((u >> 16) & 1u)) >> 16;
    return (unsigned short)r;
}
__device__ __forceinline__ float bf2f(unsigned h){
    return __uint_as_float(h << 16);
}
__device__ __forceinline__ float sqdist3(float dx, float dy, float dz){
    // numpy order, no fma contraction: ((dx*dx)+(dy*dy))+(dz*dz)
    return __fadd_rn(__fadd_rn(__fmul_rn(dx,dx), __fmul_rn(dy,dy)), __fmul_rn(dz,dz));
}
__device__ __forceinline__ int spread4(int v){ // bits 0..3 -> 0,3,6,9
    return (v&1) | ((v&2)<<2) | ((v&4)<<4) | ((v&8)<<6);
}

// DPP u64 max step: VALU-speed cross-lane (no LDS pipe round-trip)
template<int CTRL>
__device__ __forceinline__ unsigned long long dpp_max_step(unsigned long long k){
    int lo = (int)(unsigned)k;
    int hi = (int)(unsigned)(k >> 32);
    int olo = __builtin_amdgcn_update_dpp(0, lo, CTRL, 0xf, 0xf, true);
    int ohi = __builtin_amdgcn_update_dpp(0, hi, CTRL, 0xf, 0xf, true);
    unsigned long long o = ((unsigned long long)(unsigned)ohi << 32) | (unsigned)olo;
    return (o > k) ? o : k;
}
// after this, lane 63 holds the wave-wide max (keys are nonneg, 0 is identity)
__device__ __forceinline__ unsigned long long wave_max_u64(unsigned long long k){
    k = dpp_max_step<0x111>(k); // row_shr:1
    k = dpp_max_step<0x112>(k); // row_shr:2
    k = dpp_max_step<0x114>(k); // row_shr:4
    k = dpp_max_step<0x118>(k); // row_shr:8  -> lane15 of each row = row max
    k = dpp_max_step<0x142>(k); // row_bcast15
    k = dpp_max_step<0x143>(k); // row_bcast31 -> lane63 = full wave max
    return k;
}

// ---------- FPS (blocks 0..7) + fused transpose (blocks 8..8+TBLK-1) ----------
__global__ __launch_bounds__(FT) void fps_kernel(const float* __restrict__ xyz,
                                                 const float* __restrict__ pts,
                                                 float* __restrict__ newxyz,
                                                 float* __restrict__ out,
                                                 float* __restrict__ xyz_n,
                                                 float* __restrict__ pts_n){
    __shared__ float sx[NN], sy[NN], sz[NN];     // original-index order
    __shared__ int   si[NN];                     // sorted -> original idx
    __shared__ int   hist[NCELL];                // sort workspace, then winner history
    __shared__ int   waveTot[FW];
    __shared__ unsigned long long cells[SS];     // one winner cell per iteration
    int tid = threadIdx.x;

    if (blockIdx.x >= 8){
        // ---------- transpose path: xyz (B,3,N)->(B,N,3), pts (B,64,N)->(B,N,64) ----------
        int gid = (blockIdx.x - 8) * FT + tid;   // 65536 = B*N
        int b = gid >> 13, i = gid & (NN - 1);
        const float* xb = xyz + (size_t)b * 3 * NN;
        float x = xb[i], y = xb[NN + i], z = xb[2 * NN + i];
        float* xd = xyz_n + ((size_t)b * NN + i) * 3;
        xd[0] = x; xd[1] = y; xd[2] = z;
        const float* pb = pts + (size_t)b * 64 * NN + i;
        float4* pd = (float4*)(pts_n + ((size_t)b * NN + i) * 64);
#pragma unroll
        for (int q = 0; q < 16; ++q){
            float4 v;
            v.x = pb[(q*4+0)*NN]; v.y = pb[(q*4+1)*NN];
            v.z = pb[(q*4+2)*NN]; v.w = pb[(q*4+3)*NN];
            pd[q] = v;
        }
        return;
    }

    int b = blockIdx.x;
    int wave = tid >> 6, lane = tid & 63;
    const float* xb = xyz + (size_t)b * 3 * NN;

    // ---- load coords to LDS (original order) + compute morton cells ----
    int cell[PPT];
#pragma unroll
    for (int j = 0; j < PPT; ++j){
        int i = tid + j * FT;
        float x = xb[i], y = xb[NN + i], z = xb[2*NN + i];
        sx[i] = x; sy[i] = y; sz[i] = z;
        int cx = min(15, max(0, (int)(x * 16.f)));
        int cy = min(15, max(0, (int)(y * 16.f)));
        int cz = min(15, max(0, (int)(z * 16.f)));
        cell[j] = spread4(cx) | (spread4(cy) << 1) | (spread4(cz) << 2);
    }
    // ---- histogram + cells init ----
#pragma unroll
    for (int k = 0; k < NCELL/FT; ++k) hist[tid * (NCELL/FT) + k] = 0;
    cells[tid] = 0ull;   // FT == SS == 1024
    __syncthreads();
#pragma unroll
    for (int j = 0; j < PPT; ++j) atomicAdd(&hist[cell[j]], 1);
    __syncthreads();
    // ---- exclusive scan over 4096 cells ----
    {
        int base0 = tid * (NCELL/FT);
        int sum4 = 0;
#pragma unroll
        for (int k = 0; k < NCELL/FT; ++k) sum4 += hist[base0 + k];
        int s = sum4;
#pragma unroll
        for (int m = 1; m < 64; m <<= 1){
            int v = __shfl_up(s, m);
            if (lane >= m) s += v;
        }
        if (lane == 63) waveTot[wave] = s;
        __syncthreads();
        int wbase = 0;
#pragma unroll
        for (int w2 = 0; w2 < FW; ++w2) if (w2 < wave) wbase += waveTot[w2];
        int run = wbase + s - sum4;
#pragma unroll
        for (int k = 0; k < NCELL/FT; ++k){
            int h = hist[base0 + k];
            hist[base0 + k] = run;
            run += h;
        }
    }
    __syncthreads();
    // ---- scatter permutation ----
#pragma unroll
    for (int j = 0; j < PPT; ++j){
        int pos = atomicAdd(&hist[cell[j]], 1);
        si[pos] = tid + j * FT;
    }
    __syncthreads();
    // ---- gather thread's contiguous sorted chunk + bbox (8 pts -> regs, no spill) ----
    float px[PPT], py[PPT], pz[PPT], dist[PPT];
    int oi[PPT];
    float bxmin =  1e30f, bxmax = -1e30f;
    float bymin =  1e30f, bymax = -1e30f;
    float bzmin =  1e30f, bzmax = -1e30f;
#pragma unroll
    for (int j = 0; j < PPT; ++j){
        int g = si[tid * PPT + j];
        oi[j] = g;
        float x = sx[g], y = sy[g], z = sz[g];
        px[j] = x; py[j] = y; pz[j] = z;
        bxmin = fminf(bxmin, x); bxmax = fmaxf(bxmax, x);
        bymin = fminf(bymin, y); bymax = fmaxf(bymax, y);
        bzmin = fminf(bzmin, z); bzmax = fmaxf(bzmax, z);
        dist[j] = __int_as_float(0x7f800000); // +inf
    }
    __syncthreads();   // hist[] now dead -> reused as winner history

    unsigned long long mykey = 0ull;      // exact chunk {maxdist, argidx} at all times
    unsigned long long lane63cache = 0ull; // valid in lane 63 only
    float tmax = __int_as_float(0x7f800000);
    int w = 0;
    for (int t = 0; t < SS; ++t){
        // reference semantics: idx[t] = CURRENT point, then compute next argmax
        if (tid == 0) hist[t] = w;
        float lx = sx[w], ly = sy[w], lz = sz[w];
        // exact-safe bbox prune: d_bb <= d_p (f32, same rounding order) for all p in chunk
        float cdx = __fsub_rn(lx, fminf(fmaxf(lx, bxmin), bxmax));
        float cdy = __fsub_rn(ly, fminf(fmaxf(ly, bymin), bymax));
        float cdz = __fsub_rn(lz, fminf(fmaxf(lz, bzmin), bzmax));
        float d_bb = sqdist3(cdx, cdy, cdz);
        bool active = d_bb < tmax;
        unsigned long long bal = __ballot(active);
        if (active){
            {
#pragma clang fp contract(off)
#pragma unroll
                for (int j = 0; j < PPT; ++j){
                    float dx = px[j] - lx;
                    float dy = py[j] - ly;
                    float dz = pz[j] - lz;
                    float d = ((dx*dx) + (dy*dy)) + (dz*dz);
                    dist[j] = fminf(dist[j], d);
                }
            }
            // depth-3 tree max
            float m0 = fmaxf(dist[0], dist[1]);
            float m1 = fmaxf(dist[2], dist[3]);
            float m2 = fmaxf(dist[4], dist[5]);
            float m3 = fmaxf(dist[6], dist[7]);
            m0 = fmaxf(m0, m1); m2 = fmaxf(m2, m3);
            float maxd = fmaxf(m0, m2);
            int bo = 0x7fffffff;
#pragma unroll
            for (int j = 0; j < PPT; ++j)
                if (dist[j] == maxd) bo = min(bo, oi[j]);
            mykey = ((unsigned long long)__float_as_uint(maxd) << 32)
                  | (unsigned)(~bo);
            tmax = maxd;
        }
        if (bal){
            unsigned long long k = wave_max_u64(mykey);
            if (lane == 63) lane63cache = k;
        }
        if (lane == 63) atomicMax(&cells[t], lane63cache);
        __syncthreads();
        unsigned long long km = cells[t];
        w = (int)(~(unsigned)km);
    }
    __syncthreads();
    // ---- coalesced writeback from history ----
    for (int t2 = tid; t2 < SS; t2 += FT){
        int hw = hist[t2];
        float x = sx[hw], y = sy[hw], z = sz[hw];
        out[(size_t)b * 3 * SS + t2]          = x;
        out[(size_t)b * 3 * SS + SS + t2]     = y;
        out[(size_t)b * 3 * SS + 2*SS + t2]   = z;
        float* nw = newxyz + ((size_t)b * SS + t2) * 3;
        nw[0] = x; nw[1] = y; nw[2] = z;
    }
}

// ---------- query ball: one wave per sample, planar coalesced reads ----------
__global__ __launch_bounds__(256) void qb_kernel(const float* __restrict__ xyz,
                                                 const float* __restrict__ newxyz,
                                                 int* __restrict__ gidx){
    int wid = (blockIdx.x * 256 + threadIdx.x) >> 6;  // sample id 0..8191
    int lane = threadIdx.x & 63;
    int b = wid >> 10;
    const float* nw = newxyz + (size_t)wid * 3;
    float cx = nw[0], cy = nw[1], cz = nw[2];
    const float* xb = xyz + (size_t)b * 3 * NN;
    int total = 0, firstIdx = -1;
    int* gout = gidx + (size_t)wid * KK;
    for (int base = 0; base < NN; base += 64){
        int i = base + lane;
        float dx = __fsub_rn(cx, xb[i]);
        float dy = __fsub_rn(cy, xb[NN + i]);
        float dz = __fsub_rn(cz, xb[2*NN + i]);
        float d2 = sqdist3(dx, dy, dz);
        bool in = (d2 <= R2C);
        unsigned long long m = __ballot(in);
        int pos = total + __popcll(m & ((1ull << lane) - 1ull));
        if (in && pos < KK) gout[pos] = i;
        if (firstIdx < 0 && m) firstIdx = base + (__ffsll((unsigned long long)m) - 1);
        total += __popcll(m);
        if (total >= KK) break;
    }
    if (total < KK){
        int f = (total > 0) ? firstIdx : (NN - 1);
        for (int p = total + lane; p < KK; p += 64) gout[p] = f;
    }
}

// ---------- layer0: gather + 67->64 matmul + stats ----------
__global__ __launch_bounds__(256) void l0_kernel(const float* __restrict__ pts_n,
                                                 const float* __restrict__ xyz_n,
                                                 const float* __restrict__ newxyz,
                                                 const int* __restrict__ gidx,
                                                 const float* __restrict__ W0,
                                                 const float* __restrict__ b0,
                                                 uint4* __restrict__ y0,
                                                 float* __restrict__ part0){
    __shared__ float lsum[4][64][2];
    int tid = threadIdx.x;
    int pixel = blockIdx.x * 256 + tid;
    int sample = pixel >> 5;
    int b = sample >> 10;
    int gi = gidx[pixel];
    int wave = tid >> 6, lane = tid & 63;

    float ff[67];
    const float4* prow = (const float4*)(pts_n + ((size_t)b * NN + gi) * 64);
#pragma unroll
    for (int q = 0; q < 16; ++q){
        float4 v = prow[q];
        ff[q*4] = v.x; ff[q*4+1] = v.y; ff[q*4+2] = v.z; ff[q*4+3] = v.w;
    }
    const float* pr = xyz_n + ((size_t)b * NN + gi) * 3;
    const float* nw = newxyz + (size_t)sample * 3;
    ff[64] = __fsub_rn(pr[0], nw[0]) / 0.2f;
    ff[65] = __fsub_rn(pr[1], nw[1]) / 0.2f;
    ff[66] = __fsub_rn(pr[2], nw[2]) / 0.2f;

    for (int oc = 0; oc < 8; ++oc){
        float acc[8];
#pragma unroll
        for (int j = 0; j < 8; ++j) acc[j] = b0[oc*8+j];
#pragma unroll
        for (int c = 0; c < 67; ++c){
            float fe = ff[c];
#pragma unroll
            for (int j = 0; j < 8; ++j) acc[j] += fe * W0[(oc*8+j)*67 + c];
        }
        uint4 pk;
        unsigned us[8];
#pragma unroll
        for (int j = 0; j < 8; ++j){
            float v = acc[j];
            float s1 = v, s2 = v * v;
#pragma unroll
            for (int m = 1; m <= 32; m <<= 1){
                s1 += __shfl_xor(s1, m);
                s2 += __shfl_xor(s2, m);
            }
            if (lane == 0){ lsum[wave][oc*8+j][0] = s1; lsum[wave][oc*8+j][1] = s2; }
            us[j] = f2bf(v);
        }
        pk.x = us[0] | (us[1] << 16);
        pk.y = us[2] | (us[3] << 16);
        pk.z = us[4] | (us[5] << 16);
        pk.w = us[6] | (us[7] << 16);
        y0[(size_t)pixel * 8 + oc] = pk;
    }
    __syncthreads();
    if (tid < 128){
        float s = lsum[0][tid>>1][tid&1] + lsum[1][tid>>1][tid&1]
                + lsum[2][tid>>1][tid&1] + lsum[3][tid>>1][tid&1];
        part0[(size_t)blockIdx.x * 128 + tid] = s;
    }
}

// ---------- layer1: bn+relu + 64->64 matmul + stats ----------
__global__ __launch_bounds__(256) void l1_kernel(const uint4* __restrict__ y0,
                                                 const float* __restrict__ scale0,
                                                 const float* __restrict__ shift0,
                                                 const float* __restrict__ W1,
                                                 const float* __restrict__ b1,
                                                 uint4* __restrict__ y1,
                                                 float* __restrict__ part1){
    __shared__ float lsum[4][64][2];
    int tid = threadIdx.x;
    int pixel = blockIdx.x * 256 + tid;
    int wave = tid >> 6, lane = tid & 63;

    float x[64];
#pragma unroll
    for (int q = 0; q < 8; ++q){
        uint4 v = y0[(size_t)pixel * 8 + q];
        unsigned w[4] = {v.x, v.y, v.z, v.w};
#pragma unroll
        for (int r = 0; r < 4; ++r){
            int c = q*8 + r*2;
            x[c]   = fmaxf(bf2f(w[r] & 0xFFFFu) * scale0[c]   + shift0[c],   0.f);
            x[c+1] = fmaxf(bf2f(w[r] >> 16)     * scale0[c+1] + shift0[c+1], 0.f);
        }
    }
    for (int oc = 0; oc < 8; ++oc){
        float acc[8];
#pragma unroll
        for (int j = 0; j < 8; ++j) acc[j] = b1[oc*8+j];
#pragma unroll
        for (int c = 0; c < 64; ++c){
            float fe = x[c];
#pragma unroll
            for (int j = 0; j < 8; ++j) acc[j] += fe * W1[(oc*8+j)*64 + c];
        }
        uint4 pk;
        unsigned us[8];
#pragma unroll
        for (int j = 0; j < 8; ++j){
            float v = acc[j];
            float s1 = v, s2 = v * v;
#pragma unroll
            for (int m = 1; m <= 32; m <<= 1){
                s1 += __shfl_xor(s1, m);
                s2 += __shfl_xor(s2, m);
            }
            if (lane == 0){ lsum[wave][oc*8+j][0] = s1; lsum[wave][oc*8+j][1] = s2; }
            us[j] = f2bf(v);
        }
        pk.x = us[0] | (us[1] << 16);
        pk.y = us[2] | (us[3] << 16);
        pk.z = us[4] | (us[5] << 16);
        pk.w = us[6] | (us[7] << 16);
        y1[(size_t)pixel * 8 + oc] = pk;
    }
    __syncthreads();
    if (tid < 128){
        float s = lsum[0][tid>>1][tid&1] + lsum[1][tid>>1][tid&1]
                + lsum[2][tid>>1][tid&1] + lsum[3][tid>>1][tid&1];
        part1[(size_t)blockIdx.x * 128 + tid] = s;
    }
}

// ---------- layer2: bn+relu + 64->128 matmul + k-max/min + stats ----------
__global__ __launch_bounds__(256) void l2_kernel(const uint4* __restrict__ y1,
                                                 const float* __restrict__ scale1,
                                                 const float* __restrict__ shift1,
                                                 const float* __restrict__ W2,
                                                 const float* __restrict__ b2,
                                                 float* __restrict__ maxmin,
                                                 float* __restrict__ part2){
    __shared__ float lsum[4][128][2];
    int tid = threadIdx.x;
    int pixel = blockIdx.x * 256 + tid;
    int sample = pixel >> 5;
    int wave = tid >> 6, lane = tid & 63;

    float x[64];
#pragma unroll
    for (int q = 0; q < 8; ++q){
        uint4 v = y1[(size_t)pixel * 8 + q];
        unsigned w[4] = {v.x, v.y, v.z, v.w};
#pragma unroll
        for (int r = 0; r < 4; ++r){
            int c = q*8 + r*2;
            x[c]   = fmaxf(bf2f(w[r] & 0xFFFFu) * scale1[c]   + shift1[c],   0.f);
            x[c+1] = fmaxf(bf2f(w[r] >> 16)     * scale1[c+1] + shift1[c+1], 0.f);
        }
    }
    for (int oc = 0; oc < 16; ++oc){
        float acc[8];
#pragma unroll
        for (int j = 0; j < 8; ++j) acc[j] = b2[oc*8+j];
#pragma unroll
        for (int c = 0; c < 64; ++c){
            float fe = x[c];
#pragma unroll
            for (int j = 0; j < 8; ++j) acc[j] += fe * W2[(oc*8+j)*64 + c];
        }
#pragma unroll
        for (int j = 0; j < 8; ++j){
            float v = acc[j];
            int ch = oc*8 + j;
            float mx = v, mn = v;
#pragma unroll
            for (int m = 1; m <= 16; m <<= 1){
                mx = fmaxf(mx, __shfl_xor(mx, m));
                mn = fminf(mn, __shfl_xor(mn, m));
            }
            float s1 = v, s2 = v * v;
#pragma unroll
            for (int m = 1; m <= 32; m <<= 1){
                s1 += __shfl_xor(s1, m);
                s2 += __shfl_xor(s2, m);
            }
            if (lane == 0){ lsum[wave][ch][0] = s1; lsum[wave][ch][1] = s2; }
            if ((tid & 31) == 0){
                float* mm = maxmin + ((size_t)sample * 128 + ch) * 2;
                mm[0] = mx; mm[1] = mn;
            }
        }
    }
    __syncthreads();
    {
        float s = lsum[0][tid>>1][tid&1] + lsum[1][tid>>1][tid&1]
                + lsum[2][tid>>1][tid&1] + lsum[3][tid>>1][tid&1];
        part2[(size_t)blockIdx.x * 256 + tid] = s;
    }
}

// ---------- finalize BN params: coalesced float4 two-stage reduce ----------
__global__ __launch_bounds__(1024) void fin_kernel(const float* __restrict__ part, int O,
                           const float* __restrict__ g, const float* __restrict__ be,
                           float* __restrict__ scale, float* __restrict__ shift){
    __shared__ float4 ls[1024];     // 16 KB
    int tid = threadIdx.x;
    int M = 2 * O;                  // 128 or 256 floats per partial row
    int V = M >> 2;                 // float4 quads per row: 32 or 64
    int NC = 1024 / V;              // chunks: 32 or 16
    int q = tid & (V - 1);
    int c = tid / V;
    int per = 1024 / NC;            // partial rows per chunk
    const float4* p4 = (const float4*)part;
    float4 s = {0.f, 0.f, 0.f, 0.f};
    for (int r = 0; r < per; ++r){
        int blk = c * per + r;
        float4 v = p4[(size_t)blk * V + q];   // coalesced: lanes span a row
        s.x += v.x; s.y += v.y; s.z += v.z; s.w += v.w;
    }
    ls[c * V + q] = s;
    __syncthreads();
    if (tid < V){
        float4 t4 = ls[tid];
        for (int c2 = 1; c2 < NC; ++c2){
            float4 v = ls[c2 * V + tid];
            t4.x += v.x; t4.y += v.y; t4.z += v.z; t4.w += v.w;
        }
        float inv = 1.0f / (float)NPIX;
        int ch0 = 2 * tid, ch1 = 2 * tid + 1;
        float mu0 = t4.x * inv;
        float var0 = t4.y * inv - mu0 * mu0;
        float sc0 = (1.0f / sqrtf(var0 + EPS)) * g[ch0];
        scale[ch0] = sc0; shift[ch0] = be[ch0] - mu0 * sc0;
        float mu1 = t4.z * inv;
        float var1 = t4.w * inv - mu1 * mu1;
        float sc1 = (1.0f / sqrtf(var1 + EPS)) * g[ch1];
        scale[ch1] = sc1; shift[ch1] = be[ch1] - mu1 * sc1;
    }
}

// ---------- output: apply BN to max/min, relu, transpose write ----------
__global__ __launch_bounds__(256) void out_kernel(const float* __restrict__ maxmin,
                                                  const float* __restrict__ scale2,
                                                  const float* __restrict__ shift2,
                                                  float* __restrict__ out){
    int gid = blockIdx.x * 256 + threadIdx.x;  // 1048576, layout (b,o,s)
    int s = gid & 1023;
    int o = (gid >> 10) & 127;
    int b = gid >> 17;
    int sample = b * 1024 + s;
    float2 mm = ((const float2*)maxmin)[(size_t)sample * 128 + o];
    float sc = scale2[o], sh = shift2[o];
    float v = (sc >= 0.f) ? mm.x : mm.y;
    out[gid] = fmaxf(v * sc + sh, 0.f);
}

extern "C" void kernel_launch(void* const* d_in, const int* in_sizes, int n_in,
                              void* d_out, int out_size, void* d_ws, size_t ws_size,
                              hipStream_t stream) {
    const float* xyz = (const float*)d_in[0];
    const float* pts = (const float*)d_in[1];
    const float* W0 = (const float*)d_in[2];
    const float* b0 = (const float*)d_in[3];
    const float* g0 = (const float*)d_in[4];
    const float* be0 = (const float*)d_in[5];
    const float* W1 = (const float*)d_in[6];
    const float* b1 = (const float*)d_in[7];
    const float* g1 = (const float*)d_in[8];
    const float* be1 = (const float*)d_in[9];
    const float* W2 = (const float*)d_in[10];
    const float* b2 = (const float*)d_in[11];
    const float* g2 = (const float*)d_in[12];
    const float* be2 = (const float*)d_in[13];

    char* ws = (char*)d_ws;
    float* newxyz = (float*)(ws + OFF_NEWXYZ);
    int*   gidx   = (int*)(ws + OFF_GIDX);
    float* xyz_n  = (float*)(ws + OFF_XYZN);
    float* pts_n  = (float*)(ws + OFF_PTSN);
    uint4* y0     = (uint4*)(ws + OFF_Y0);
    uint4* y1     = (uint4*)(ws + OFF_Y1);
    float* maxmin = (float*)(ws + OFF_MAXMIN);
    float* part0  = (float*)(ws + OFF_P0);
    float* part1  = (float*)(ws + OFF_P1);
    float* part2  = (float*)(ws + OFF_P2);
    float* sc     = (float*)(ws + OFF_SC);
    float* scale0 = sc,        *shift0 = sc + 64;
    float* scale1 = sc + 128,  *shift1 = sc + 192;
    float* scale2 = sc + 256,  *shift2 = sc + 384;

    float* out = (float*)d_out;
    float* out_np = out + BB * 3 * SS;

    hipLaunchKernelGGL(fps_kernel, dim3(8 + TBLK), dim3(FT), 0, stream,
                       xyz, pts, newxyz, out, xyz_n, pts_n);
    hipLaunchKernelGGL(qb_kernel, dim3(2048), dim3(256), 0, stream, xyz, newxyz, gidx);
    hipLaunchKernelGGL(l0_kernel, dim3(1024), dim3(256), 0, stream,
                       pts_n, xyz_n, newxyz, gidx, W0, b0, y0, part0);
    hipLaunchKernelGGL(fin_kernel, dim3(1), dim3(1024), 0, stream, part0, 64, g0, be0, scale0, shift0);
    hipLaunchKernelGGL(l1_kernel, dim3(1024), dim3(256), 0, stream,
                       y0, scale0, shift0, W1, b1, y1, part1);
    hipLaunchKernelGGL(fin_kernel, dim3(1), dim3(1024), 0, stream, part1, 64, g1, be1, scale1, shift1);
    hipLaunchKernelGGL(l2_kernel, dim3(1024), dim3(256), 0, stream,
                       y1, scale1, shift1, W2, b2, maxmin, part2);
    hipLaunchKernelGGL(fin_kernel, dim3(1), dim3(1024), 0, stream, part2, 128, g2, be2, scale2, shift2);
    hipLaunchKernelGGL(out_kernel, dim3(4096), dim3(256), 0, stream, maxmin, scale2, shift2, out_np);
}

// Round 9
// 1238.063 us; speedup vs baseline: 1.5529x; 1.0026x over previous
//
#include <hip/hip_runtime.h>

#define BB 8
#define NN 8192
#define SS 1024
#define KK 32
#define NPIX (BB*SS*KK)   // 262144
#define R2C 0.04f
#define EPS 1e-5f

#define FT 1024           // fps threads (16 waves)
#define FW (FT/64)        // 16 waves
#define PPT (NN/FT)       // 8 points per thread  -> arrays fit registers, no scratch
#define NCELL 4096        // 16^3 morton cells
#define TBLK 64           // transpose blocks fused into fps launch

typedef float v2f __attribute__((ext_vector_type(2)));

// ---------- ws layout (bytes) ----------
#define OFF_IDX      0u
#define OFF_NEWXYZ   (OFF_IDX + BB*SS*4)
#define OFF_GIDX     (OFF_NEWXYZ + BB*SS*3*4)
#define OFF_XYZN     (OFF_GIDX + BB*SS*KK*4)
#define OFF_PTSN     (OFF_XYZN + BB*NN*3*4)
#define OFF_Y0       (OFF_PTSN + BB*NN*64*4)
#define OFF_Y1       (OFF_Y0 + NPIX*64*2)
#define OFF_MAXMIN   (OFF_Y1 + NPIX*64*2)
#define OFF_P0       (OFF_MAXMIN + BB*SS*128*2*4)
#define OFF_P1       (OFF_P0 + 1024*128*4)
#define OFF_P2       (OFF_P1 + 1024*128*4)
#define OFF_SC       (OFF_P2 + 1024*256*4)

__device__ __forceinline__ unsigned short f2bf(float x){
    unsigned u = __float_as_uint(x);
    unsigned r = (u + 0x7FFFu + ((u >> 16) & 1u)) >> 16;
    return (unsigned short)r;
}
__device__ __forceinline__ float bf2f(unsigned h){
    return __uint_as_float(h << 16);
}
__device__ __forceinline__ float sqdist3(float dx, float dy, float dz){
    // numpy order, no fma contraction: ((dx*dx)+(dy*dy))+(dz*dz)
    return __fadd_rn(__fadd_rn(__fmul_rn(dx,dx), __fmul_rn(dy,dy)), __fmul_rn(dz,dz));
}
__device__ __forceinline__ int spread4(int v){ // bits 0..3 -> 0,3,6,9
    return (v&1) | ((v&2)<<2) | ((v&4)<<4) | ((v&8)<<6);
}

// ---- DPP u64 max (FPS argmax keys) ----
template<int CTRL>
__device__ __forceinline__ unsigned long long dpp_max_step(unsigned long long k){
    int lo = (int)(unsigned)k;
    int hi = (int)(unsigned)(k >> 32);
    int olo = __builtin_amdgcn_update_dpp(0, lo, CTRL, 0xf, 0xf, true);
    int ohi = __builtin_amdgcn_update_dpp(0, hi, CTRL, 0xf, 0xf, true);
    unsigned long long o = ((unsigned long long)(unsigned)ohi << 32) | (unsigned)olo;
    return (o > k) ? o : k;
}
__device__ __forceinline__ unsigned long long wave_max_u64(unsigned long long k){
    k = dpp_max_step<0x111>(k); k = dpp_max_step<0x112>(k);
    k = dpp_max_step<0x114>(k); k = dpp_max_step<0x118>(k);
    k = dpp_max_step<0x142>(k); k = dpp_max_step<0x143>(k); // lane63 = wave max
    return k;
}

// ---- DPP f32 reductions (layer stats): VALU-speed, off the LDS pipe ----
template<int CTRL>
__device__ __forceinline__ float dpp_sum_step(float v){
    int o = __builtin_amdgcn_update_dpp(0, __float_as_int(v), CTRL, 0xf, 0xf, true);
    return v + __int_as_float(o);
}
__device__ __forceinline__ float wave_sum_f32(float v){   // lane63 = sum over 64
    v = dpp_sum_step<0x111>(v); v = dpp_sum_step<0x112>(v);
    v = dpp_sum_step<0x114>(v); v = dpp_sum_step<0x118>(v);
    v = dpp_sum_step<0x142>(v); v = dpp_sum_step<0x143>(v);
    return v;
}
template<int CTRL>
__device__ __forceinline__ float dpp_max_stepf(float v){
    int o = __builtin_amdgcn_update_dpp(__float_as_int(v), __float_as_int(v), CTRL, 0xf, 0xf, false);
    return fmaxf(v, __int_as_float(o));
}
template<int CTRL>
__device__ __forceinline__ float dpp_min_stepf(float v){
    int o = __builtin_amdgcn_update_dpp(__float_as_int(v), __float_as_int(v), CTRL, 0xf, 0xf, false);
    return fminf(v, __int_as_float(o));
}
__device__ __forceinline__ float grp32_max(float v){      // lanes 31/63 = group max
    v = dpp_max_stepf<0x111>(v); v = dpp_max_stepf<0x112>(v);
    v = dpp_max_stepf<0x114>(v); v = dpp_max_stepf<0x118>(v);
    v = dpp_max_stepf<0x142>(v);
    return v;
}
__device__ __forceinline__ float grp32_min(float v){      // lanes 31/63 = group min
    v = dpp_min_stepf<0x111>(v); v = dpp_min_stepf<0x112>(v);
    v = dpp_min_stepf<0x114>(v); v = dpp_min_stepf<0x118>(v);
    v = dpp_min_stepf<0x142>(v);
    return v;
}

// ---------- FPS (blocks 0..7) + fused transpose (blocks 8..8+TBLK-1) ----------
__global__ __launch_bounds__(FT) void fps_kernel(const float* __restrict__ xyz,
                                                 const float* __restrict__ pts,
                                                 float* __restrict__ newxyz,
                                                 float* __restrict__ out,
                                                 float* __restrict__ xyz_n,
                                                 float* __restrict__ pts_n){
    __shared__ float sxyz[NN * 3];               // interleaved x,y,z per point
    __shared__ int   si[NN];                     // sorted -> original idx
    __shared__ int   hist[NCELL];                // sort workspace, then winner history
    __shared__ int   waveTot[FW];
    __shared__ unsigned long long cells[SS];     // one winner cell per iteration
    int tid = threadIdx.x;

    if (blockIdx.x >= 8){
        // ---------- transpose path: xyz (B,3,N)->(B,N,3), pts (B,64,N)->(B,N,64) ----------
        int gid = (blockIdx.x - 8) * FT + tid;   // 65536 = B*N
        int b = gid >> 13, i = gid & (NN - 1);
        const float* xb = xyz + (size_t)b * 3 * NN;
        float x = xb[i], y = xb[NN + i], z = xb[2 * NN + i];
        float* xd = xyz_n + ((size_t)b * NN + i) * 3;
        xd[0] = x; xd[1] = y; xd[2] = z;
        const float* pb = pts + (size_t)b * 64 * NN + i;
        float4* pd = (float4*)(pts_n + ((size_t)b * NN + i) * 64);
#pragma unroll
        for (int q = 0; q < 16; ++q){
            float4 v;
            v.x = pb[(q*4+0)*NN]; v.y = pb[(q*4+1)*NN];
            v.z = pb[(q*4+2)*NN]; v.w = pb[(q*4+3)*NN];
            pd[q] = v;
        }
        return;
    }

    int b = blockIdx.x;
    int wave = tid >> 6, lane = tid & 63;
    const float* xb = xyz + (size_t)b * 3 * NN;

    // ---- load coords to LDS (original order) + compute morton cells ----
    int cell[PPT];
#pragma unroll
    for (int j = 0; j < PPT; ++j){
        int i = tid + j * FT;
        float x = xb[i], y = xb[NN + i], z = xb[2*NN + i];
        sxyz[i*3]   = x; sxyz[i*3+1] = y; sxyz[i*3+2] = z;
        int cx = min(15, max(0, (int)(x * 16.f)));
        int cy = min(15, max(0, (int)(y * 16.f)));
        int cz = min(15, max(0, (int)(z * 16.f)));
        cell[j] = spread4(cx) | (spread4(cy) << 1) | (spread4(cz) << 2);
    }
    // ---- histogram + cells init ----
#pragma unroll
    for (int k = 0; k < NCELL/FT; ++k) hist[tid * (NCELL/FT) + k] = 0;
    cells[tid] = 0ull;   // FT == SS == 1024
    __syncthreads();
#pragma unroll
    for (int j = 0; j < PPT; ++j) atomicAdd(&hist[cell[j]], 1);
    __syncthreads();
    // ---- exclusive scan over 4096 cells ----
    {
        int base0 = tid * (NCELL/FT);
        int sum4 = 0;
#pragma unroll
        for (int k = 0; k < NCELL/FT; ++k) sum4 += hist[base0 + k];
        int s = sum4;
#pragma unroll
        for (int m = 1; m < 64; m <<= 1){
            int v = __shfl_up(s, m);
            if (lane >= m) s += v;
        }
        if (lane == 63) waveTot[wave] = s;
        __syncthreads();
        int wbase = 0;
#pragma unroll
        for (int w2 = 0; w2 < FW; ++w2) if (w2 < wave) wbase += waveTot[w2];
        int run = wbase + s - sum4;
#pragma unroll
        for (int k = 0; k < NCELL/FT; ++k){
            int h = hist[base0 + k];
            hist[base0 + k] = run;
            run += h;
        }
    }
    __syncthreads();
    // ---- scatter permutation ----
#pragma unroll
    for (int j = 0; j < PPT; ++j){
        int pos = atomicAdd(&hist[cell[j]], 1);
        si[pos] = tid + j * FT;
    }
    __syncthreads();
    // ---- gather thread's contiguous sorted chunk + bbox (packed v2f regs) ----
    v2f px[PPT/2], py[PPT/2], pz[PPT/2];
    float dist[PPT];
    int oi[PPT];
    float bxmin =  1e30f, bxmax = -1e30f;
    float bymin =  1e30f, bymax = -1e30f;
    float bzmin =  1e30f, bzmax = -1e30f;
#pragma unroll
    for (int j = 0; j < PPT; ++j){
        int g = si[tid * PPT + j];
        oi[j] = g;
        float x = sxyz[g*3], y = sxyz[g*3+1], z = sxyz[g*3+2];
        px[j>>1][j&1] = x; py[j>>1][j&1] = y; pz[j>>1][j&1] = z;
        bxmin = fminf(bxmin, x); bxmax = fmaxf(bxmax, x);
        bymin = fminf(bymin, y); bymax = fmaxf(bymax, y);
        bzmin = fminf(bzmin, z); bzmax = fmaxf(bzmax, z);
        dist[j] = __int_as_float(0x7f800000); // +inf
    }
    __syncthreads();   // hist[] now dead -> reused as winner history

    unsigned long long mykey = 0ull;      // exact chunk {maxdist, argidx} at all times
    unsigned long long lane63cache = 0ull; // valid in lane 63 only
    float tmax = __int_as_float(0x7f800000);
    int w = 0;
    for (int t = 0; t < SS; ++t){
        // reference semantics: idx[t] = CURRENT point, then compute next argmax
        if (tid == 0) hist[t] = w;
        int w3 = w * 3;
        float lx = sxyz[w3], ly = sxyz[w3+1], lz = sxyz[w3+2];
        // exact-safe bbox prune: d_bb <= d_p (f32, same rounding order) for all p in chunk
        float cdx = __fsub_rn(lx, fminf(fmaxf(lx, bxmin), bxmax));
        float cdy = __fsub_rn(ly, fminf(fmaxf(ly, bymin), bymax));
        float cdz = __fsub_rn(lz, fminf(fmaxf(lz, bzmin), bzmax));
        float d_bb = sqdist3(cdx, cdy, cdz);
        bool active = d_bb < tmax;
        unsigned long long bal = __ballot(active);
        if (active){
            {
#pragma clang fp contract(off)
                v2f lx2 = {lx, lx}, ly2 = {ly, ly}, lz2 = {lz, lz};
#pragma unroll
                for (int p = 0; p < PPT/2; ++p){
                    v2f dx = px[p] - lx2;          // v_pk_add_f32 (IEEE per-op)
                    v2f dy = py[p] - ly2;
                    v2f dz = pz[p] - lz2;
                    v2f d  = ((dx*dx) + (dy*dy)) + (dz*dz);  // numpy order, no fma
                    dist[2*p]   = fminf(dist[2*p],   d[0]);
                    dist[2*p+1] = fminf(dist[2*p+1], d[1]);
                }
            }
            // depth-3 tree max
            float m0 = fmaxf(dist[0], dist[1]);
            float m1 = fmaxf(dist[2], dist[3]);
            float m2 = fmaxf(dist[4], dist[5]);
            float m3 = fmaxf(dist[6], dist[7]);
            m0 = fmaxf(m0, m1); m2 = fmaxf(m2, m3);
            float maxd = fmaxf(m0, m2);
            int bo = 0x7fffffff;
#pragma unroll
            for (int j = 0; j < PPT; ++j)
                if (dist[j] == maxd) bo = min(bo, oi[j]);
            mykey = ((unsigned long long)__float_as_uint(maxd) << 32)
                  | (unsigned)(~bo);
            tmax = maxd;
        }
        if (bal){
            unsigned long long k = wave_max_u64(mykey);
            if (lane == 63) lane63cache = k;
        }
        if (lane == 63) atomicMax(&cells[t], lane63cache);
        __syncthreads();
        unsigned long long km = cells[t];
        w = (int)(~(unsigned)km);
    }
    __syncthreads();
    // ---- coalesced writeback from history ----
    for (int t2 = tid; t2 < SS; t2 += FT){
        int hw = hist[t2] * 3;
        float x = sxyz[hw], y = sxyz[hw+1], z = sxyz[hw+2];
        out[(size_t)b * 3 * SS + t2]          = x;
        out[(size_t)b * 3 * SS + SS + t2]     = y;
        out[(size_t)b * 3 * SS + 2*SS + t2]   = z;
        float* nw = newxyz + ((size_t)b * SS + t2) * 3;
        nw[0] = x; nw[1] = y; nw[2] = z;
    }
}

// ---------- query ball: one wave per sample, planar coalesced reads ----------
__global__ __launch_bounds__(256) void qb_kernel(const float* __restrict__ xyz,
                                                 const float* __restrict__ newxyz,
                                                 int* __restrict__ gidx){
    int wid = (blockIdx.x * 256 + threadIdx.x) >> 6;  // sample id 0..8191
    int lane = threadIdx.x & 63;
    int b = wid >> 10;
    const float* nw = newxyz + (size_t)wid * 3;
    float cx = nw[0], cy = nw[1], cz = nw[2];
    const float* xb = xyz + (size_t)b * 3 * NN;
    int total = 0, firstIdx = -1;
    int* gout = gidx + (size_t)wid * KK;
    for (int base = 0; base < NN; base += 64){
        int i = base + lane;
        float dx = __fsub_rn(cx, xb[i]);
        float dy = __fsub_rn(cy, xb[NN + i]);
        float dz = __fsub_rn(cz, xb[2*NN + i]);
        float d2 = sqdist3(dx, dy, dz);
        bool in = (d2 <= R2C);
        unsigned long long m = __ballot(in);
        int pos = total + __popcll(m & ((1ull << lane) - 1ull));
        if (in && pos < KK) gout[pos] = i;
        if (firstIdx < 0 && m) firstIdx = base + (__ffsll((unsigned long long)m) - 1);
        total += __popcll(m);
        if (total >= KK) break;
    }
    if (total < KK){
        int f = (total > 0) ? firstIdx : (NN - 1);
        for (int p = total + lane; p < KK; p += 64) gout[p] = f;
    }
}

// ---------- layer0: gather + 67->64 matmul + stats ----------
__global__ __launch_bounds__(256) void l0_kernel(const float* __restrict__ pts_n,
                                                 const float* __restrict__ xyz_n,
                                                 const float* __restrict__ newxyz,
                                                 const int* __restrict__ gidx,
                                                 const float* __restrict__ W0,
                                                 const float* __restrict__ b0,
                                                 uint4* __restrict__ y0,
                                                 float* __restrict__ part0){
    __shared__ float lsum[4][64][2];
    int tid = threadIdx.x;
    int pixel = blockIdx.x * 256 + tid;
    int sample = pixel >> 5;
    int b = sample >> 10;
    int gi = gidx[pixel];
    int wave = tid >> 6, lane = tid & 63;

    float ff[67];
    const float4* prow = (const float4*)(pts_n + ((size_t)b * NN + gi) * 64);
#pragma unroll
    for (int q = 0; q < 16; ++q){
        float4 v = prow[q];
        ff[q*4] = v.x; ff[q*4+1] = v.y; ff[q*4+2] = v.z; ff[q*4+3] = v.w;
    }
    const float* pr = xyz_n + ((size_t)b * NN + gi) * 3;
    const float* nw = newxyz + (size_t)sample * 3;
    ff[64] = __fsub_rn(pr[0], nw[0]) / 0.2f;
    ff[65] = __fsub_rn(pr[1], nw[1]) / 0.2f;
    ff[66] = __fsub_rn(pr[2], nw[2]) / 0.2f;

    for (int oc = 0; oc < 8; ++oc){
        float acc[8];
#pragma unroll
        for (int j = 0; j < 8; ++j) acc[j] = b0[oc*8+j];
#pragma unroll
        for (int c = 0; c < 67; ++c){
            float fe = ff[c];
#pragma unroll
            for (int j = 0; j < 8; ++j) acc[j] += fe * W0[(oc*8+j)*67 + c];
        }
        uint4 pk;
        unsigned us[8];
#pragma unroll
        for (int j = 0; j < 8; ++j){
            float v = acc[j];
            float s1 = wave_sum_f32(v);
            float s2 = wave_sum_f32(v * v);
            if (lane == 63){ lsum[wave][oc*8+j][0] = s1; lsum[wave][oc*8+j][1] = s2; }
            us[j] = f2bf(v);
        }
        pk.x = us[0] | (us[1] << 16);
        pk.y = us[2] | (us[3] << 16);
        pk.z = us[4] | (us[5] << 16);
        pk.w = us[6] | (us[7] << 16);
        y0[(size_t)pixel * 8 + oc] = pk;
    }
    __syncthreads();
    if (tid < 128){
        float s = lsum[0][tid>>1][tid&1] + lsum[1][tid>>1][tid&1]
                + lsum[2][tid>>1][tid&1] + lsum[3][tid>>1][tid&1];
        part0[(size_t)blockIdx.x * 128 + tid] = s;
    }
}

// ---------- layer1: bn+relu + 64->64 matmul + stats ----------
__global__ __launch_bounds__(256) void l1_kernel(const uint4* __restrict__ y0,
                                                 const float* __restrict__ scale0,
                                                 const float* __restrict__ shift0,
                                                 const float* __restrict__ W1,
                                                 const float* __restrict__ b1,
                                                 uint4* __restrict__ y1,
                                                 float* __restrict__ part1){
    __shared__ float lsum[4][64][2];
    int tid = threadIdx.x;
    int pixel = blockIdx.x * 256 + tid;
    int wave = tid >> 6, lane = tid & 63;

    float x[64];
#pragma unroll
    for (int q = 0; q < 8; ++q){
        uint4 v = y0[(size_t)pixel * 8 + q];
        unsigned w[4] = {v.x, v.y, v.z, v.w};
#pragma unroll
        for (int r = 0; r < 4; ++r){
            int c = q*8 + r*2;
            x[c]   = fmaxf(bf2f(w[r] & 0xFFFFu) * scale0[c]   + shift0[c],   0.f);
            x[c+1] = fmaxf(bf2f(w[r] >> 16)     * scale0[c+1] + shift0[c+1], 0.f);
        }
    }
    for (int oc = 0; oc < 8; ++oc){
        float acc[8];
#pragma unroll
        for (int j = 0; j < 8; ++j) acc[j] = b1[oc*8+j];
#pragma unroll
        for (int c = 0; c < 64; ++c){
            float fe = x[c];
#pragma unroll
            for (int j = 0; j < 8; ++j) acc[j] += fe * W1[(oc*8+j)*64 + c];
        }
        uint4 pk;
        unsigned us[8];
#pragma unroll
        for (int j = 0; j < 8; ++j){
            float v = acc[j];
            float s1 = wave_sum_f32(v);
            float s2 = wave_sum_f32(v * v);
            if (lane == 63){ lsum[wave][oc*8+j][0] = s1; lsum[wave][oc*8+j][1] = s2; }
            us[j] = f2bf(v);
        }
        pk.x = us[0] | (us[1] << 16);
        pk.y = us[2] | (us[3] << 16);
        pk.z = us[4] | (us[5] << 16);
        pk.w = us[6] | (us[7] << 16);
        y1[(size_t)pixel * 8 + oc] = pk;
    }
    __syncthreads();
    if (tid < 128){
        float s = lsum[0][tid>>1][tid&1] + lsum[1][tid>>1][tid&1]
                + lsum[2][tid>>1][tid&1] + lsum[3][tid>>1][tid&1];
        part1[(size_t)blockIdx.x * 128 + tid] = s;
    }
}

// ---------- layer2: bn+relu + 64->128 matmul + k-max/min + stats ----------
__global__ __launch_bounds__(256) void l2_kernel(const uint4* __restrict__ y1,
                                                 const float* __restrict__ scale1,
                                                 const float* __restrict__ shift1,
                                                 const float* __restrict__ W2,
                                                 const float* __restrict__ b2,
                                                 float* __restrict__ maxmin,
                                                 float* __restrict__ part2){
    __shared__ float lsum[4][128][2];
    int tid = threadIdx.x;
    int pixel = blockIdx.x * 256 + tid;
    int sample = pixel >> 5;
    int wave = tid >> 6, lane = tid & 63;

    float x[64];
#pragma unroll
    for (int q = 0; q < 8; ++q){
        uint4 v = y1[(size_t)pixel * 8 + q];
        unsigned w[4] = {v.x, v.y, v.z, v.w};
#pragma unroll
        for (int r = 0; r < 4; ++r){
            int c = q*8 + r*2;
            x[c]   = fmaxf(bf2f(w[r] & 0xFFFFu) * scale1[c]   + shift1[c],   0.f);
            x[c+1] = fmaxf(bf2f(w[r] >> 16)     * scale1[c+1] + shift1[c+1], 0.f);
        }
    }
    for (int oc = 0; oc < 16; ++oc){
        float acc[8];
#pragma unroll
        for (int j = 0; j < 8; ++j) acc[j] = b2[oc*8+j];
#pragma unroll
        for (int c = 0; c < 64; ++c){
            float fe = x[c];
#pragma unroll
            for (int j = 0; j < 8; ++j) acc[j] += fe * W2[(oc*8+j)*64 + c];
        }
#pragma unroll
        for (int j = 0; j < 8; ++j){
            float v = acc[j];
            int ch = oc*8 + j;
            float mx = grp32_max(v);   // valid in lanes 31/63
            float mn = grp32_min(v);
            float s1 = wave_sum_f32(v);
            float s2 = wave_sum_f32(v * v);
            if (lane == 63){ lsum[wave][ch][0] = s1; lsum[wave][ch][1] = s2; }
            if ((tid & 31) == 31){
                float* mm = maxmin + ((size_t)sample * 128 + ch) * 2;
                mm[0] = mx; mm[1] = mn;
            }
        }
    }
    __syncthreads();
    {
        float s = lsum[0][tid>>1][tid&1] + lsum[1][tid>>1][tid&1]
                + lsum[2][tid>>1][tid&1] + lsum[3][tid>>1][tid&1];
        part2[(size_t)blockIdx.x * 256 + tid] = s;
    }
}

// ---------- finalize BN params: coalesced float4 two-stage reduce ----------
__global__ __launch_bounds__(1024) void fin_kernel(const float* __restrict__ part, int O,
                           const float* __restrict__ g, const float* __restrict__ be,
                           float* __restrict__ scale, float* __restrict__ shift){
    __shared__ float4 ls[1024];     // 16 KB
    int tid = threadIdx.x;
    int M = 2 * O;                  // 128 or 256 floats per partial row
    int V = M >> 2;                 // float4 quads per row: 32 or 64
    int NC = 1024 / V;              // chunks: 32 or 16
    int q = tid & (V - 1);
    int c = tid / V;
    int per = 1024 / NC;            // partial rows per chunk
    const float4* p4 = (const float4*)part;
    float4 s = {0.f, 0.f, 0.f, 0.f};
    for (int r = 0; r < per; ++r){
        int blk = c * per + r;
        float4 v = p4[(size_t)blk * V + q];   // coalesced: lanes span a row
        s.x += v.x; s.y += v.y; s.z += v.z; s.w += v.w;
    }
    ls[c * V + q] = s;
    __syncthreads();
    if (tid < V){
        float4 t4 = ls[tid];
        for (int c2 = 1; c2 < NC; ++c2){
            float4 v = ls[c2 * V + tid];
            t4.x += v.x; t4.y += v.y; t4.z += v.z; t4.w += v.w;
        }
        float inv = 1.0f / (float)NPIX;
        int ch0 = 2 * tid, ch1 = 2 * tid + 1;
        float mu0 = t4.x * inv;
        float var0 = t4.y * inv - mu0 * mu0;
        float sc0 = (1.0f / sqrtf(var0 + EPS)) * g[ch0];
        scale[ch0] = sc0; shift[ch0] = be[ch0] - mu0 * sc0;
        float mu1 = t4.z * inv;
        float var1 = t4.w * inv - mu1 * mu1;
        float sc1 = (1.0f / sqrtf(var1 + EPS)) * g[ch1];
        scale[ch1] = sc1; shift[ch1] = be[ch1] - mu1 * sc1;
    }
}

// ---------- output: apply BN to max/min, relu, transpose write ----------
__global__ __launch_bounds__(256) void out_kernel(const float* __restrict__ maxmin,
                                                  const float* __restrict__ scale2,
                                                  const float* __restrict__ shift2,
                                                  float* __restrict__ out){
    int gid = blockIdx.x * 256 + threadIdx.x;  // 1048576, layout (b,o,s)
    int s = gid & 1023;
    int o = (gid >> 10) & 127;
    int b = gid >> 17;
    int sample = b * 1024 + s;
    float2 mm = ((const float2*)maxmin)[(size_t)sample * 128 + o];
    float sc = scale2[o], sh = shift2[o];
    float v = (sc >= 0.f) ? mm.x : mm.y;
    out[gid] = fmaxf(v * sc + sh, 0.f);
}

extern "C" void kernel_launch(void* const* d_in, const int* in_sizes, int n_in,
                              void* d_out, int out_size, void* d_ws, size_t ws_size,
                              hipStream_t stream) {
    const float* xyz = (const float*)d_in[0];
    const float* pts = (const float*)d_in[1];
    const float* W0 = (const float*)d_in[2];
    const float* b0 = (const float*)d_in[3];
    const float* g0 = (const float*)d_in[4];
    const float* be0 = (const float*)d_in[5];
    const float* W1 = (const float*)d_in[6];
    const float* b1 = (const float*)d_in[7];
    const float* g1 = (const float*)d_in[8];
    const float* be1 = (const float*)d_in[9];
    const float* W2 = (const float*)d_in[10];
    const float* b2 = (const float*)d_in[11];
    const float* g2 = (const float*)d_in[12];
    const float* be2 = (const float*)d_in[13];

    char* ws = (char*)d_ws;
    float* newxyz = (float*)(ws + OFF_NEWXYZ);
    int*   gidx   = (int*)(ws + OFF_GIDX);
    float* xyz_n  = (float*)(ws + OFF_XYZN);
    float* pts_n  = (float*)(ws + OFF_PTSN);
    uint4* y0     = (uint4*)(ws + OFF_Y0);
    uint4* y1     = (uint4*)(ws + OFF_Y1);
    float* maxmin = (float*)(ws + OFF_MAXMIN);
    float* part0  = (float*)(ws + OFF_P0);
    float* part1  = (float*)(ws + OFF_P1);
    float* part2  = (float*)(ws + OFF_P2);
    float* sc     = (float*)(ws + OFF_SC);
    float* scale0 = sc,        *shift0 = sc + 64;
    float* scale1 = sc + 128,  *shift1 = sc + 192;
    float* scale2 = sc + 256,  *shift2 = sc + 384;

    float* out = (float*)d_out;
    float* out_np = out + BB * 3 * SS;

    hipLaunchKernelGGL(fps_kernel, dim3(8 + TBLK), dim3(FT), 0, stream,
                       xyz, pts, newxyz, out, xyz_n, pts_n);
    hipLaunchKernelGGL(qb_kernel, dim3(2048), dim3(256), 0, stream, xyz, newxyz, gidx);
    hipLaunchKernelGGL(l0_kernel, dim3(1024), dim3(256), 0, stream,
                       pts_n, xyz_n, newxyz, gidx, W0, b0, y0, part0);
    hipLaunchKernelGGL(fin_kernel, dim3(1), dim3(1024), 0, stream, part0, 64, g0, be0, scale0, shift0);
    hipLaunchKernelGGL(l1_kernel, dim3(1024), dim3(256), 0, stream,
                       y0, scale0, shift0, W1, b1, y1, part1);
    hipLaunchKernelGGL(fin_kernel, dim3(1), dim3(1024), 0, stream, part1, 64, g1, be1, scale1, shift1);
    hipLaunchKernelGGL(l2_kernel, dim3(1024), dim3(256), 0, stream,
                       y1, scale1, shift1, W2, b2, maxmin, part2);
    hipLaunchKernelGGL(fin_kernel, dim3(1), dim3(1024), 0, stream, part2, 128, g2, be2, scale2, shift2);
    hipLaunchKernelGGL(out_kernel, dim3(4096), dim3(256), 0, stream, maxmin, scale2, shift2, out_np);
}